// Round 1
// baseline (3007.520 us; speedup 1.0000x reference)
//
#include <hip/hip_runtime.h>
#include <math.h>

#define NEMP   3000
#define NSHIFT 30000
#define NVAR   500000
#define ESD    960000
#define EVE    500000
#define EVS    500000

__device__ __forceinline__ float wredsum(float v) {
  #pragma unroll
  for (int o = 32; o > 0; o >>= 1) v += __shfl_xor(v, o);
  return v;
}

// ---------------- Stage 0: feature projection  out = relu(x @ W + b) ----------------
template<int F>
__global__ __launch_bounds__(256) void proj_kernel(const float* __restrict__ x,
    const float* __restrict__ W, const float* __restrict__ b,
    float* __restrict__ out, int N) {
  int n = __builtin_amdgcn_readfirstlane((int)(blockIdx.x * 4 + (threadIdx.x >> 6)));
  int j = threadIdx.x & 63;
  if (n >= N) return;
  const float* xr = x + (size_t)n * F;
  float acc = b[j];
  #pragma unroll
  for (int f = 0; f < F; ++f) acc = fmaf(xr[f], W[f * 64 + j], acc);
  out[(size_t)n * 64 + j] = fmaxf(acc, 0.0f);
}

// out = h @ W (+ b optional), 64->64
__global__ __launch_bounds__(256) void linear64_kernel(const float* __restrict__ h,
    const float* __restrict__ W, const float* __restrict__ b,
    float* __restrict__ out, int N) {
  int n = __builtin_amdgcn_readfirstlane((int)(blockIdx.x * 4 + (threadIdx.x >> 6)));
  int j = threadIdx.x & 63;
  if (n >= N) return;
  const float* hr = h + (size_t)n * 64;
  float acc = b ? b[j] : 0.0f;
  #pragma unroll
  for (int f = 0; f < 64; ++f) acc = fmaf(hr[f], W[f * 64 + j], acc);
  out[(size_t)n * 64 + j] = acc;
}

// ---------------- Stage 1a: X = h_shift @ gat_W ; a_s/a_d per (node, head) ----------------
__global__ __launch_bounds__(256) void gat_x_kernel(const float* __restrict__ h,
    const float* __restrict__ gat_W, const float* __restrict__ att_src,
    const float* __restrict__ att_dst, float* __restrict__ X,
    float* __restrict__ a_s, float* __restrict__ a_d, int N) {
  __shared__ float Wl[64 * 256];           // 64 KB: stage gat_W once per block
  int c = threadIdx.x;                     // 0..255 = head*64 + dim
  for (int f = 0; f < 64; ++f) Wl[f * 256 + c] = gat_W[f * 256 + c];
  __syncthreads();
  int h4 = c >> 6, d = c & 63;
  float asrc = att_src[h4 * 64 + d], adst = att_dst[h4 * 64 + d];
  int n0 = blockIdx.x * 8;
  for (int k = 0; k < 8; ++k) {
    int n = n0 + k;
    if (n >= N) break;
    const float* hr = h + (size_t)n * 64;
    float acc = 0.0f;
    #pragma unroll
    for (int f = 0; f < 64; ++f) acc = fmaf(hr[f], Wl[f * 256 + c], acc);
    X[(size_t)n * 256 + c] = acc;
    float ps = wredsum(acc * asrc);
    float pd = wredsum(acc * adst);
    if (d == 0) { a_s[n * 4 + h4] = ps; a_d[n * 4 + h4] = pd; }
  }
}

// ---------------- CSR build: count -> scan(3 phase) -> fill ----------------
__global__ __launch_bounds__(256) void count_kernel(const int* __restrict__ key, int E,
                                                    int* __restrict__ cnt) {
  for (int i = blockIdx.x * 256 + threadIdx.x; i < E; i += gridDim.x * 256)
    atomicAdd(&cnt[key[i]], 1);
}

__global__ __launch_bounds__(256) void scan_phase1(const int* __restrict__ cnt, int N,
                                                   int* __restrict__ partial) {
  __shared__ int sd[256];
  int t = threadIdx.x;
  int base = blockIdx.x * 1024 + t * 4;
  int s = 0;
  #pragma unroll
  for (int k = 0; k < 4; ++k) { int i = base + k; if (i < N) s += cnt[i]; }
  sd[t] = s; __syncthreads();
  for (int o = 128; o > 0; o >>= 1) { if (t < o) sd[t] += sd[t + o]; __syncthreads(); }
  if (t == 0) partial[blockIdx.x] = sd[0];
}

__global__ __launch_bounds__(512) void scan_phase2(int* __restrict__ partial, int B) {
  __shared__ int sd[512];
  int t = threadIdx.x;
  int v = (t < B) ? partial[t] : 0;
  sd[t] = v; __syncthreads();
  for (int o = 1; o < 512; o <<= 1) {
    int add = (t >= o) ? sd[t - o] : 0;
    __syncthreads();
    sd[t] += add;
    __syncthreads();
  }
  if (t < B) partial[t] = sd[t] - v;   // exclusive
}

// writes row[] and overwrites cnt[] with the running cursor (== row start)
__global__ __launch_bounds__(256) void scan_phase3(int* __restrict__ cnt, int N,
    const int* __restrict__ partial, int* __restrict__ row) {
  __shared__ int sd[256];
  int t = threadIdx.x;
  int base = blockIdx.x * 1024 + t * 4;
  int v[4]; int s = 0;
  #pragma unroll
  for (int k = 0; k < 4; ++k) { int i = base + k; v[k] = (i < N) ? cnt[i] : 0; s += v[k]; }
  sd[t] = s; __syncthreads();
  for (int o = 1; o < 256; o <<= 1) {
    int add = (t >= o) ? sd[t - o] : 0;
    __syncthreads();
    sd[t] += add;
    __syncthreads();
  }
  int run = partial[blockIdx.x] + sd[t] - s;
  #pragma unroll
  for (int k = 0; k < 4; ++k) {
    int i = base + k;
    if (i < N) {
      row[i] = run; cnt[i] = run; run += v[k];
      if (i == N - 1) row[N] = run;
    }
  }
}

__global__ __launch_bounds__(256) void fill_kernel(const int* __restrict__ key,
    const int* __restrict__ val, int E, int* __restrict__ cursor, int* __restrict__ elist) {
  for (int i = blockIdx.x * 256 + threadIdx.x; i < E; i += gridDim.x * 256) {
    int pos = atomicAdd(&cursor[key[i]], 1);
    elist[pos] = val[i];
  }
}

// ---------------- Stage 1b: GAT aggregate (wave per dst node, lane = dim) ----------------
__global__ __launch_bounds__(256) void gat_aggr_kernel(const float* __restrict__ X,
    const float* __restrict__ a_s, const float* __restrict__ a_d,
    const int* __restrict__ row, const int* __restrict__ elist,
    const float* __restrict__ gat_b, const float* __restrict__ h0,
    float* __restrict__ h1, int N) {
  int n = __builtin_amdgcn_readfirstlane((int)(blockIdx.x * 4 + (threadIdx.x >> 6)));
  int l = threadIdx.x & 63;
  if (n >= N) return;
  int beg = row[n], end = row[n + 1];
  float ad0 = a_d[n * 4 + 0], ad1 = a_d[n * 4 + 1], ad2 = a_d[n * 4 + 2], ad3 = a_d[n * 4 + 3];
  float z0 = 0, z1 = 0, z2 = 0, z3 = 0, c0 = 0, c1 = 0, c2 = 0, c3 = 0;
  for (int p = beg; p < end; ++p) {
    int s = elist[p];
    float e0 = a_s[s * 4 + 0] + ad0, e1 = a_s[s * 4 + 1] + ad1;
    float e2 = a_s[s * 4 + 2] + ad2, e3 = a_s[s * 4 + 3] + ad3;
    e0 = e0 > 0.f ? e0 : 0.2f * e0;  e1 = e1 > 0.f ? e1 : 0.2f * e1;
    e2 = e2 > 0.f ? e2 : 0.2f * e2;  e3 = e3 > 0.f ? e3 : 0.2f * e3;
    float x0 = __expf(e0), x1 = __expf(e1), x2 = __expf(e2), x3 = __expf(e3);
    z0 += x0; z1 += x1; z2 += x2; z3 += x3;
    const float* Xr = X + (size_t)s * 256;
    c0 = fmaf(x0, Xr[l], c0);
    c1 = fmaf(x1, Xr[64 + l], c1);
    c2 = fmaf(x2, Xr[128 + l], c2);
    c3 = fmaf(x3, Xr[192 + l], c3);
  }
  float o = 0.25f * (c0 / fmaxf(z0, 1e-16f) + c1 / fmaxf(z1, 1e-16f) +
                     c2 / fmaxf(z2, 1e-16f) + c3 / fmaxf(z3, 1e-16f));
  o += gat_b[l];
  h1[(size_t)n * 64 + l] = fmaxf(o, 0.0f) + h0[(size_t)n * 64 + l];
}

// ---------------- Stage 2+3 fused: inject(emp) + inject(shift) + fuse matmul + L2 norm ----
__global__ __launch_bounds__(256) void stage2_kernel(
    const float* __restrict__ h_var,
    const float* __restrict__ qWe, const float* __restrict__ Ke, const float* __restrict__ Vpe,
    const int* __restrict__ ve_row, const int* __restrict__ ve_src,
    const float* __restrict__ qWs, const float* __restrict__ Ks, const float* __restrict__ Vps,
    const int* __restrict__ vs_row, const int* __restrict__ vs_src,
    const float* __restrict__ fuseW, const float* __restrict__ fuseb,
    float* __restrict__ out, int N) {
  __shared__ float fT[192][65];   // [t][node-col], stride 65 -> conflict-free both phases
  __shared__ float ssq[4][64];
  int l = threadIdx.x & 63;
  int w = __builtin_amdgcn_readfirstlane((int)(threadIdx.x >> 6));
  int blockStart = blockIdx.x * 64;

  // Phase A: each wave owns 16 consecutive node-columns; lane = hidden dim
  for (int k = 0; k < 16; ++k) {
    int c = w * 16 + k;
    int n = blockStart + c;
    if (n >= N) break;
    float hv = h_var[(size_t)n * 64 + l];
    fT[l][c] = hv;
    // ---- inject from employees ----
    {
      int b = ve_row[n], e = ve_row[n + 1];
      float msg = 0.0f;
      if (e > b) {
        float q = 0.0f;
        #pragma unroll
        for (int i = 0; i < 64; ++i) q = fmaf(fT[i][c], qWe[i * 64 + l], q);
        float z = 0.0f, acc = 0.0f;
        for (int p = b; p < e; ++p) {
          int s = ve_src[p];
          float pr = wredsum(q * Ke[s * 64 + l]);
          float ex = __expf(pr * 0.125f);
          z += ex;
          acc = fmaf(ex, Vpe[s * 64 + l], acc);
        }
        msg = acc / fmaxf(z, 1e-9f);
      }
      fT[64 + l][c] = msg;
    }
    // ---- inject from shifts ----
    {
      int b = vs_row[n], e = vs_row[n + 1];
      float msg = 0.0f;
      if (e > b) {
        float q = 0.0f;
        #pragma unroll
        for (int i = 0; i < 64; ++i) q = fmaf(fT[i][c], qWs[i * 64 + l], q);
        float z = 0.0f, acc = 0.0f;
        for (int p = b; p < e; ++p) {
          int s = vs_src[p];
          float pr = wredsum(q * Ks[s * 64 + l]);
          float ex = __expf(pr * 0.125f);
          z += ex;
          acc = fmaf(ex, Vps[s * 64 + l], acc);
        }
        msg = acc / fmaxf(z, 1e-9f);
      }
      fT[128 + l][c] = msg;
    }
  }
  __syncthreads();

  // Phase B: lane = node-col; wave w computes outputs j = w*16 .. w*16+15 (scalar W loads)
  float acc[16];
  #pragma unroll
  for (int jj = 0; jj < 16; ++jj) acc[jj] = 0.0f;
  for (int t = 0; t < 192; ++t) {
    float f = fT[t][l];
    const float* wr = fuseW + t * 64 + w * 16;   // wave-uniform -> s_load
    #pragma unroll
    for (int jj = 0; jj < 16; ++jj) acc[jj] = fmaf(f, wr[jj], acc[jj]);
  }
  float ss = 0.0f;
  #pragma unroll
  for (int jj = 0; jj < 16; ++jj) {
    float v = fmaxf(acc[jj] + fuseb[w * 16 + jj], 0.0f);
    ss += v * v;
  }
  ssq[w][l] = ss;
  __syncthreads();
  if (w == 0) {
    int n = blockStart + l;
    if (n < N) out[n] = sqrtf(ssq[0][l] + ssq[1][l] + ssq[2][l] + ssq[3][l]);
  }
}

// ---------------- host ----------------
extern "C" void kernel_launch(void* const* d_in, const int* in_sizes, int n_in,
                              void* d_out, int out_size, void* d_ws, size_t ws_size,
                              hipStream_t stream) {
  const float* x_emp   = (const float*)d_in[0];
  const float* x_shift = (const float*)d_in[1];
  const float* x_var   = (const float*)d_in[2];
  const float* W_emp   = (const float*)d_in[4];
  const float* b_emp   = (const float*)d_in[5];
  const float* W_shift = (const float*)d_in[6];
  const float* b_shift = (const float*)d_in[7];
  const float* W_var   = (const float*)d_in[8];
  const float* b_var   = (const float*)d_in[9];
  const float* gat_W   = (const float*)d_in[12];
  const float* att_s   = (const float*)d_in[13];
  const float* att_d   = (const float*)d_in[14];
  const float* gat_b   = (const float*)d_in[15];
  const float* injW_e  = (const float*)d_in[16];
  const float* injb_e  = (const float*)d_in[17];
  const float* injW_s  = (const float*)d_in[18];
  const float* injb_s  = (const float*)d_in[19];
  const float* qW_e    = (const float*)d_in[20];
  const float* kW_e    = (const float*)d_in[21];
  const float* qW_s    = (const float*)d_in[22];
  const float* kW_s    = (const float*)d_in[23];
  const float* fuseW   = (const float*)d_in[24];
  const float* fuseb   = (const float*)d_in[25];
  const int* sd_src  = (const int*)d_in[26];
  const int* sd_dst  = (const int*)d_in[27];
  const int* ve_var  = (const int*)d_in[28];
  const int* ve_emp  = (const int*)d_in[29];
  const int* vs_var  = (const int*)d_in[30];
  const int* vs_shift= (const int*)d_in[31];
  float* out = (float*)d_out;

  char* base = (char*)d_ws;
  size_t off = 0;
  auto A = [&](size_t nbytes) -> void* {
    void* r = base + off;
    off = (off + nbytes + 255) & ~(size_t)255;
    return r;
  };
  float* h_emp = (float*)A((size_t)NEMP * 64 * 4);
  float* h_sh0 = (float*)A((size_t)NSHIFT * 64 * 4);
  float* h_sh1 = (float*)A((size_t)NSHIFT * 64 * 4);
  float* h_var = (float*)A((size_t)NVAR * 64 * 4);
  float* Xg    = (float*)A((size_t)NSHIFT * 256 * 4);
  float* a_s   = (float*)A((size_t)NSHIFT * 4 * 4);
  float* a_d   = (float*)A((size_t)NSHIFT * 4 * 4);
  float* Vpe   = (float*)A((size_t)NEMP * 64 * 4);
  float* Keb   = (float*)A((size_t)NEMP * 64 * 4);
  float* Vps   = (float*)A((size_t)NSHIFT * 64 * 4);
  float* Ksb   = (float*)A((size_t)NSHIFT * 64 * 4);
  int* cnt_sd  = (int*)A((size_t)NSHIFT * 4);
  int* cnt_ve  = (int*)A((size_t)NVAR * 4);
  int* cnt_vs  = (int*)A((size_t)NVAR * 4);
  int* row_sd  = (int*)A((size_t)(NSHIFT + 1) * 4);
  int* row_ve  = (int*)A((size_t)(NVAR + 1) * 4);
  int* row_vs  = (int*)A((size_t)(NVAR + 1) * 4);
  int* el_sd   = (int*)A((size_t)ESD * 4);
  int* el_ve   = (int*)A((size_t)EVE * 4);
  int* el_vs   = (int*)A((size_t)EVS * 4);
  int* partial = (int*)A(512 * 4);

  hipMemsetAsync(cnt_sd, 0, (size_t)NSHIFT * 4, stream);
  hipMemsetAsync(cnt_ve, 0, (size_t)NVAR * 4, stream);
  hipMemsetAsync(cnt_vs, 0, (size_t)NVAR * 4, stream);

  auto buildCSR = [&](const int* key, const int* val, int E, int Nn,
                      int* cnt, int* row, int* elist) {
    int gE = (E + 255) / 256; if (gE > 2048) gE = 2048;
    count_kernel<<<gE, 256, 0, stream>>>(key, E, cnt);
    int B = (Nn + 1023) / 1024;
    scan_phase1<<<B, 256, 0, stream>>>(cnt, Nn, partial);
    scan_phase2<<<1, 512, 0, stream>>>(partial, B);
    scan_phase3<<<B, 256, 0, stream>>>(cnt, Nn, partial, row);
    fill_kernel<<<gE, 256, 0, stream>>>(key, val, E, cnt, elist);
  };

  // Stage 0 projections (h_con unused -> skipped)
  proj_kernel<32><<<(NEMP + 3) / 4, 256, 0, stream>>>(x_emp, W_emp, b_emp, h_emp, NEMP);
  proj_kernel<24><<<(NSHIFT + 3) / 4, 256, 0, stream>>>(x_shift, W_shift, b_shift, h_sh0, NSHIFT);
  proj_kernel<19><<<(NVAR + 3) / 4, 256, 0, stream>>>(x_var, W_var, b_var, h_var, NVAR);

  // Stage 1: GAT
  gat_x_kernel<<<(NSHIFT + 7) / 8, 256, 0, stream>>>(h_sh0, gat_W, att_s, att_d, Xg, a_s, a_d, NSHIFT);
  buildCSR(sd_dst, sd_src, ESD, NSHIFT, cnt_sd, row_sd, el_sd);
  gat_aggr_kernel<<<(NSHIFT + 3) / 4, 256, 0, stream>>>(Xg, a_s, a_d, row_sd, el_sd,
                                                        gat_b, h_sh0, h_sh1, NSHIFT);

  // Stage 2 prep: entity-side transforms
  linear64_kernel<<<(NEMP + 3) / 4, 256, 0, stream>>>(h_emp, injW_e, injb_e, Vpe, NEMP);
  linear64_kernel<<<(NEMP + 3) / 4, 256, 0, stream>>>(h_emp, kW_e, nullptr, Keb, NEMP);
  linear64_kernel<<<(NSHIFT + 3) / 4, 256, 0, stream>>>(h_sh1, injW_s, injb_s, Vps, NSHIFT);
  linear64_kernel<<<(NSHIFT + 3) / 4, 256, 0, stream>>>(h_sh1, kW_s, nullptr, Ksb, NSHIFT);

  buildCSR(ve_var, ve_emp, EVE, NVAR, cnt_ve, row_ve, el_ve);
  buildCSR(vs_var, vs_shift, EVS, NVAR, cnt_vs, row_vs, el_vs);

  // Stage 2+3 fused
  stage2_kernel<<<(NVAR + 63) / 64, 256, 0, stream>>>(h_var,
      qW_e, Keb, Vpe, row_ve, el_ve,
      qW_s, Ksb, Vps, row_vs, el_vs,
      fuseW, fuseb, out, NVAR);
}

// Round 2
// 838.050 us; speedup vs baseline: 3.5887x; 3.5887x over previous
//
#include <hip/hip_runtime.h>
#include <math.h>

#define NEMP   3000
#define NSHIFT 30000
#define NVAR   500000
#define ESD    960000
#define EVE    500000
#define EVS    500000

// ---------------- Stage 0: feature projection  out = relu(x @ W + b) ----------------
template<int F>
__global__ __launch_bounds__(256) void proj_kernel(const float* __restrict__ x,
    const float* __restrict__ W, const float* __restrict__ b,
    float* __restrict__ out, int N) {
  int n = __builtin_amdgcn_readfirstlane((int)(blockIdx.x * 4 + (threadIdx.x >> 6)));
  int j = threadIdx.x & 63;
  if (n >= N) return;
  const float* xr = x + (size_t)n * F;
  float acc = b[j];
  #pragma unroll
  for (int f = 0; f < F; ++f) acc = fmaf(xr[f], W[f * 64 + j], acc);
  out[(size_t)n * 64 + j] = fmaxf(acc, 0.0f);
}

// out = h @ W (+ b optional), 64->64
__global__ __launch_bounds__(256) void linear64_kernel(const float* __restrict__ h,
    const float* __restrict__ W, const float* __restrict__ b,
    float* __restrict__ out, int N) {
  int n = __builtin_amdgcn_readfirstlane((int)(blockIdx.x * 4 + (threadIdx.x >> 6)));
  int j = threadIdx.x & 63;
  if (n >= N) return;
  const float* hr = h + (size_t)n * 64;
  float acc = b ? b[j] : 0.0f;
  #pragma unroll
  for (int f = 0; f < 64; ++f) acc = fmaf(hr[f], W[f * 64 + j], acc);
  out[(size_t)n * 64 + j] = acc;
}

// W2[f*64+j] = 0.125 * sum_d qW[j*64+d] * kW[f*64+d]   (folds Q@K^T + 1/sqrt(H))
__global__ __launch_bounds__(256) void qkfold_kernel(const float* __restrict__ qW,
    const float* __restrict__ kW, float* __restrict__ W2) {
  int j = threadIdx.x & 63;
  int fq = threadIdx.x >> 6;
  for (int ff = 0; ff < 16; ++ff) {
    int f = fq * 16 + ff;
    float acc = 0.0f;
    #pragma unroll
    for (int d = 0; d < 64; ++d) acc = fmaf(qW[j * 64 + d], kW[f * 64 + d], acc);
    W2[f * 64 + j] = 0.125f * acc;
  }
}

// ---------------- Stage 1a: X = h_shift @ gat_W ; a_s/a_d per (node, head) ----------------
__global__ __launch_bounds__(256) void gat_x_kernel(const float* __restrict__ h,
    const float* __restrict__ gat_W, const float* __restrict__ att_src,
    const float* __restrict__ att_dst, float* __restrict__ X,
    float* __restrict__ a_s, float* __restrict__ a_d, int N) {
  __shared__ float Wl[64 * 256];           // 64 KB: stage gat_W once per block
  int c = threadIdx.x;                     // 0..255 = head*64 + dim
  for (int f = 0; f < 64; ++f) Wl[f * 256 + c] = gat_W[f * 256 + c];
  __syncthreads();
  int h4 = c >> 6, d = c & 63;
  float asrc = att_src[h4 * 64 + d], adst = att_dst[h4 * 64 + d];
  int n0 = blockIdx.x * 8;
  for (int k = 0; k < 8; ++k) {
    int n = n0 + k;
    if (n >= N) break;
    const float* hr = h + (size_t)n * 64;
    float acc = 0.0f;
    #pragma unroll
    for (int f = 0; f < 64; ++f) acc = fmaf(hr[f], Wl[f * 256 + c], acc);
    X[(size_t)n * 256 + c] = acc;
    float ps = acc * asrc, pd = acc * adst;
    #pragma unroll
    for (int o = 32; o > 0; o >>= 1) { ps += __shfl_xor(ps, o); pd += __shfl_xor(pd, o); }
    if (d == 0) { a_s[n * 4 + h4] = ps; a_d[n * 4 + h4] = pd; }
  }
}

// ---------------- CSR build: count -> scan(3 phase) -> fill ----------------
__global__ __launch_bounds__(256) void count_kernel(const int* __restrict__ key, int E,
                                                    int* __restrict__ cnt) {
  for (int i = blockIdx.x * 256 + threadIdx.x; i < E; i += gridDim.x * 256)
    atomicAdd(&cnt[key[i]], 1);
}

__global__ __launch_bounds__(256) void scan_phase1(const int* __restrict__ cnt, int N,
                                                   int* __restrict__ partial) {
  __shared__ int sd[256];
  int t = threadIdx.x;
  int base = blockIdx.x * 1024 + t * 4;
  int s = 0;
  #pragma unroll
  for (int k = 0; k < 4; ++k) { int i = base + k; if (i < N) s += cnt[i]; }
  sd[t] = s; __syncthreads();
  for (int o = 128; o > 0; o >>= 1) { if (t < o) sd[t] += sd[t + o]; __syncthreads(); }
  if (t == 0) partial[blockIdx.x] = sd[0];
}

__global__ __launch_bounds__(512) void scan_phase2(int* __restrict__ partial, int B) {
  __shared__ int sd[512];
  int t = threadIdx.x;
  int v = (t < B) ? partial[t] : 0;
  sd[t] = v; __syncthreads();
  for (int o = 1; o < 512; o <<= 1) {
    int add = (t >= o) ? sd[t - o] : 0;
    __syncthreads();
    sd[t] += add;
    __syncthreads();
  }
  if (t < B) partial[t] = sd[t] - v;   // exclusive
}

// writes row[] and overwrites cnt[] with the running cursor (== row start)
__global__ __launch_bounds__(256) void scan_phase3(int* __restrict__ cnt, int N,
    const int* __restrict__ partial, int* __restrict__ row) {
  __shared__ int sd[256];
  int t = threadIdx.x;
  int base = blockIdx.x * 1024 + t * 4;
  int v[4]; int s = 0;
  #pragma unroll
  for (int k = 0; k < 4; ++k) { int i = base + k; v[k] = (i < N) ? cnt[i] : 0; s += v[k]; }
  sd[t] = s; __syncthreads();
  for (int o = 1; o < 256; o <<= 1) {
    int add = (t >= o) ? sd[t - o] : 0;
    __syncthreads();
    sd[t] += add;
    __syncthreads();
  }
  int run = partial[blockIdx.x] + sd[t] - s;
  #pragma unroll
  for (int k = 0; k < 4; ++k) {
    int i = base + k;
    if (i < N) {
      row[i] = run; cnt[i] = run; run += v[k];
      if (i == N - 1) row[N] = run;
    }
  }
}

__global__ __launch_bounds__(256) void fill_kernel(const int* __restrict__ key,
    const int* __restrict__ val, int E, int* __restrict__ cursor, int* __restrict__ elist) {
  for (int i = blockIdx.x * 256 + threadIdx.x; i < E; i += gridDim.x * 256) {
    int pos = atomicAdd(&cursor[key[i]], 1);
    elist[pos] = val[i];
  }
}

// ---------------- Stage 1b: GAT aggregate (wave per dst node; 16-lane subgroup = head) ----
__global__ __launch_bounds__(256) void gat_aggr_kernel(const float* __restrict__ X,
    const float* __restrict__ a_s, const float* __restrict__ a_d,
    const int* __restrict__ row, const int* __restrict__ elist,
    const float* __restrict__ gat_b, const float* __restrict__ h0,
    float* __restrict__ h1, int N) {
  int n = __builtin_amdgcn_readfirstlane((int)(blockIdx.x * 4 + (threadIdx.x >> 6)));
  int l = threadIdx.x & 63;
  if (n >= N) return;
  int g = l >> 4, sl = l & 15;      // g = head, sl*4.. = dims
  int beg = row[n], end = row[n + 1];
  float ad = a_d[n * 4 + g];
  float4 acc = make_float4(0.f, 0.f, 0.f, 0.f);
  float z = 0.0f;
  for (int p = beg; p < end; ++p) {
    int s = elist[p];
    float e = a_s[s * 4 + g] + ad;
    e = e > 0.0f ? e : 0.2f * e;
    float ex = __expf(e);
    z += ex;
    const float4 x4 = *(const float4*)(X + (size_t)s * 256 + g * 64 + sl * 4);
    acc.x = fmaf(ex, x4.x, acc.x); acc.y = fmaf(ex, x4.y, acc.y);
    acc.z = fmaf(ex, x4.z, acc.z); acc.w = fmaf(ex, x4.w, acc.w);
  }
  float inv = 0.25f / fmaxf(z, 1e-16f);
  float4 v = make_float4(acc.x * inv, acc.y * inv, acc.z * inv, acc.w * inv);
  v.x += __shfl_xor(v.x, 16); v.x += __shfl_xor(v.x, 32);
  v.y += __shfl_xor(v.y, 16); v.y += __shfl_xor(v.y, 32);
  v.z += __shfl_xor(v.z, 16); v.z += __shfl_xor(v.z, 32);
  v.w += __shfl_xor(v.w, 16); v.w += __shfl_xor(v.w, 32);
  if (g == 0) {
    const float4 b4 = *(const float4*)(gat_b + sl * 4);
    const float4 h04 = *(const float4*)(h0 + (size_t)n * 64 + sl * 4);
    float4 o;
    o.x = fmaxf(v.x + b4.x, 0.0f) + h04.x;
    o.y = fmaxf(v.y + b4.y, 0.0f) + h04.y;
    o.z = fmaxf(v.z + b4.z, 0.0f) + h04.z;
    o.w = fmaxf(v.w + b4.w, 0.0f) + h04.w;
    *(float4*)(h1 + (size_t)n * 64 + sl * 4) = o;
  }
}

// ---------------- Stage 2+3 fused: inject x2 (q-folded) + fuse matmul + L2 norm ----------
__global__ __launch_bounds__(512) void stage2_kernel(
    const float* __restrict__ h_var,
    const float* __restrict__ K2e, const float* __restrict__ Vpe,
    const int* __restrict__ ve_row, const int* __restrict__ ve_src,
    const float* __restrict__ K2s, const float* __restrict__ Vps,
    const int* __restrict__ vs_row, const int* __restrict__ vs_src,
    const float* __restrict__ fuseW, const float* __restrict__ fuseb,
    float* __restrict__ out, int N) {
  __shared__ float fT[192][65];   // [t][node-col]
  __shared__ float ssq[8][64];
  int tid = threadIdx.x;
  int lane = tid & 63;
  int w = __builtin_amdgcn_readfirstlane((int)(tid >> 6));   // 0..7
  int g = lane >> 4, sl = lane & 15;                         // subgroup, sub-lane
  int blockStart = blockIdx.x * 64;

  // Phase A: wave w owns node-cols w*8 .. w*8+7; 4 subgroups x 2 rounds
  for (int k = 0; k < 2; ++k) {
    int c = w * 8 + k * 4 + g;
    int n = blockStart + c;
    bool act = (n < N);
    float4 hv = act ? *(const float4*)(h_var + (size_t)n * 64 + sl * 4)
                    : make_float4(0.f, 0.f, 0.f, 0.f);
    fT[sl * 4 + 0][c] = hv.x; fT[sl * 4 + 1][c] = hv.y;
    fT[sl * 4 + 2][c] = hv.z; fT[sl * 4 + 3][c] = hv.w;

    #pragma unroll
    for (int which = 0; which < 2; ++which) {
      const int*   rowp = which ? vs_row : ve_row;
      const int*   srcp = which ? vs_src : ve_src;
      const float* K2   = which ? K2s : K2e;
      const float* Vp   = which ? Vps : Vpe;
      int outBase = which ? 128 : 64;
      int b = 0, e = 0;
      if (act) { b = rowp[n]; e = rowp[n + 1]; }
      float4 acc = make_float4(0.f, 0.f, 0.f, 0.f);
      float z = 0.0f;
      for (int p = b; p < e; ++p) {
        int s = srcp[p];
        const float4 k4 = *(const float4*)(K2 + (size_t)s * 64 + sl * 4);
        float part = hv.x * k4.x + hv.y * k4.y + hv.z * k4.z + hv.w * k4.w;
        part += __shfl_xor(part, 1); part += __shfl_xor(part, 2);
        part += __shfl_xor(part, 4); part += __shfl_xor(part, 8);
        float ex = __expf(part);          // scale already folded into K2
        z += ex;
        const float4 v4 = *(const float4*)(Vp + (size_t)s * 64 + sl * 4);
        acc.x = fmaf(ex, v4.x, acc.x); acc.y = fmaf(ex, v4.y, acc.y);
        acc.z = fmaf(ex, v4.z, acc.z); acc.w = fmaf(ex, v4.w, acc.w);
      }
      float inv = (e > b) ? 1.0f / fmaxf(z, 1e-9f) : 0.0f;
      fT[outBase + sl * 4 + 0][c] = acc.x * inv;
      fT[outBase + sl * 4 + 1][c] = acc.y * inv;
      fT[outBase + sl * 4 + 2][c] = acc.z * inv;
      fT[outBase + sl * 4 + 3][c] = acc.w * inv;
    }
  }
  __syncthreads();

  // Phase B: lane = node-col; wave w computes outputs j = w*8 .. w*8+7
  float acc[8];
  #pragma unroll
  for (int jj = 0; jj < 8; ++jj) acc[jj] = 0.0f;
  for (int t = 0; t < 192; ++t) {
    float f = fT[t][lane];
    const float* wr = fuseW + t * 64 + w * 8;   // wave-uniform -> s_load
    #pragma unroll
    for (int jj = 0; jj < 8; ++jj) acc[jj] = fmaf(f, wr[jj], acc[jj]);
  }
  float ss = 0.0f;
  #pragma unroll
  for (int jj = 0; jj < 8; ++jj) {
    float v = fmaxf(acc[jj] + fuseb[w * 8 + jj], 0.0f);
    ss += v * v;
  }
  ssq[w][lane] = ss;
  __syncthreads();
  if (w == 0) {
    int n = blockStart + lane;
    float s2 = 0.0f;
    #pragma unroll
    for (int i = 0; i < 8; ++i) s2 += ssq[i][lane];
    if (n < N) out[n] = sqrtf(s2);
  }
}

// ---------------- host ----------------
extern "C" void kernel_launch(void* const* d_in, const int* in_sizes, int n_in,
                              void* d_out, int out_size, void* d_ws, size_t ws_size,
                              hipStream_t stream) {
  const float* x_emp   = (const float*)d_in[0];
  const float* x_shift = (const float*)d_in[1];
  const float* x_var   = (const float*)d_in[2];
  const float* W_emp   = (const float*)d_in[4];
  const float* b_emp   = (const float*)d_in[5];
  const float* W_shift = (const float*)d_in[6];
  const float* b_shift = (const float*)d_in[7];
  const float* W_var   = (const float*)d_in[8];
  const float* b_var   = (const float*)d_in[9];
  const float* gat_W   = (const float*)d_in[12];
  const float* att_s   = (const float*)d_in[13];
  const float* att_d   = (const float*)d_in[14];
  const float* gat_b   = (const float*)d_in[15];
  const float* injW_e  = (const float*)d_in[16];
  const float* injb_e  = (const float*)d_in[17];
  const float* injW_s  = (const float*)d_in[18];
  const float* injb_s  = (const float*)d_in[19];
  const float* qW_e    = (const float*)d_in[20];
  const float* kW_e    = (const float*)d_in[21];
  const float* qW_s    = (const float*)d_in[22];
  const float* kW_s    = (const float*)d_in[23];
  const float* fuseW   = (const float*)d_in[24];
  const float* fuseb   = (const float*)d_in[25];
  const int* sd_src  = (const int*)d_in[26];
  const int* sd_dst  = (const int*)d_in[27];
  const int* ve_var  = (const int*)d_in[28];
  const int* ve_emp  = (const int*)d_in[29];
  const int* vs_var  = (const int*)d_in[30];
  const int* vs_shift= (const int*)d_in[31];
  float* out = (float*)d_out;

  char* base = (char*)d_ws;
  size_t off = 0;
  auto A = [&](size_t nbytes) -> void* {
    void* r = base + off;
    off = (off + nbytes + 255) & ~(size_t)255;
    return r;
  };
  float* h_emp = (float*)A((size_t)NEMP * 64 * 4);
  float* h_sh0 = (float*)A((size_t)NSHIFT * 64 * 4);
  float* h_sh1 = (float*)A((size_t)NSHIFT * 64 * 4);
  float* h_var = (float*)A((size_t)NVAR * 64 * 4);
  float* Xg    = (float*)A((size_t)NSHIFT * 256 * 4);
  float* a_s   = (float*)A((size_t)NSHIFT * 4 * 4);
  float* a_d   = (float*)A((size_t)NSHIFT * 4 * 4);
  float* Vpe   = (float*)A((size_t)NEMP * 64 * 4);
  float* K2e   = (float*)A((size_t)NEMP * 64 * 4);
  float* Vps   = (float*)A((size_t)NSHIFT * 64 * 4);
  float* K2s   = (float*)A((size_t)NSHIFT * 64 * 4);
  float* W2e   = (float*)A((size_t)64 * 64 * 4);
  float* W2s   = (float*)A((size_t)64 * 64 * 4);
  int* cnt_sd  = (int*)A((size_t)NSHIFT * 4);
  int* cnt_ve  = (int*)A((size_t)NVAR * 4);
  int* cnt_vs  = (int*)A((size_t)NVAR * 4);
  int* row_sd  = (int*)A((size_t)(NSHIFT + 1) * 4);
  int* row_ve  = (int*)A((size_t)(NVAR + 1) * 4);
  int* row_vs  = (int*)A((size_t)(NVAR + 1) * 4);
  int* el_sd   = (int*)A((size_t)ESD * 4);
  int* el_ve   = (int*)A((size_t)EVE * 4);
  int* el_vs   = (int*)A((size_t)EVS * 4);
  int* partial = (int*)A(512 * 4);

  hipMemsetAsync(cnt_sd, 0, (size_t)NSHIFT * 4, stream);
  hipMemsetAsync(cnt_ve, 0, (size_t)NVAR * 4, stream);
  hipMemsetAsync(cnt_vs, 0, (size_t)NVAR * 4, stream);

  auto buildCSR = [&](const int* key, const int* val, int E, int Nn,
                      int* cnt, int* row, int* elist) {
    int gE = (E + 255) / 256; if (gE > 2048) gE = 2048;
    count_kernel<<<gE, 256, 0, stream>>>(key, E, cnt);
    int B = (Nn + 1023) / 1024;
    scan_phase1<<<B, 256, 0, stream>>>(cnt, Nn, partial);
    scan_phase2<<<1, 512, 0, stream>>>(partial, B);
    scan_phase3<<<B, 256, 0, stream>>>(cnt, Nn, partial, row);
    fill_kernel<<<gE, 256, 0, stream>>>(key, val, E, cnt, elist);
  };

  // Stage 0 projections (h_con unused -> skipped)
  proj_kernel<32><<<(NEMP + 3) / 4, 256, 0, stream>>>(x_emp, W_emp, b_emp, h_emp, NEMP);
  proj_kernel<24><<<(NSHIFT + 3) / 4, 256, 0, stream>>>(x_shift, W_shift, b_shift, h_sh0, NSHIFT);
  proj_kernel<19><<<(NVAR + 3) / 4, 256, 0, stream>>>(x_var, W_var, b_var, h_var, NVAR);

  // Stage 1: GAT
  gat_x_kernel<<<(NSHIFT + 7) / 8, 256, 0, stream>>>(h_sh0, gat_W, att_s, att_d, Xg, a_s, a_d, NSHIFT);
  buildCSR(sd_dst, sd_src, ESD, NSHIFT, cnt_sd, row_sd, el_sd);
  gat_aggr_kernel<<<(NSHIFT + 3) / 4, 256, 0, stream>>>(Xg, a_s, a_d, row_sd, el_sd,
                                                        gat_b, h_sh0, h_sh1, NSHIFT);

  // Stage 2 prep: fold q/k weight products, entity-side transforms
  qkfold_kernel<<<1, 256, 0, stream>>>(qW_e, kW_e, W2e);
  qkfold_kernel<<<1, 256, 0, stream>>>(qW_s, kW_s, W2s);
  linear64_kernel<<<(NEMP + 3) / 4, 256, 0, stream>>>(h_emp, injW_e, injb_e, Vpe, NEMP);
  linear64_kernel<<<(NEMP + 3) / 4, 256, 0, stream>>>(h_emp, W2e, nullptr, K2e, NEMP);
  linear64_kernel<<<(NSHIFT + 3) / 4, 256, 0, stream>>>(h_sh1, injW_s, injb_s, Vps, NSHIFT);
  linear64_kernel<<<(NSHIFT + 3) / 4, 256, 0, stream>>>(h_sh1, W2s, nullptr, K2s, NSHIFT);

  buildCSR(ve_var, ve_emp, EVE, NVAR, cnt_ve, row_ve, el_ve);
  buildCSR(vs_var, vs_shift, EVS, NVAR, cnt_vs, row_vs, el_vs);

  // Stage 2+3 fused
  stage2_kernel<<<(NVAR + 63) / 64, 512, 0, stream>>>(h_var,
      K2e, Vpe, row_ve, el_ve,
      K2s, Vps, row_vs, el_vs,
      fuseW, fuseb, out, NVAR);
}

// Round 3
// 779.000 us; speedup vs baseline: 3.8607x; 1.0758x over previous
//
#include <hip/hip_runtime.h>
#include <math.h>

#define NEMP   3000
#define NSHIFT 30000
#define NVAR   500000
#define ESD    960000
#define EVE    500000
#define EVS    500000
#define NT_CNT (NSHIFT + NVAR + NVAR)      // combined segment count
#define ET_ALL (ESD + EVE + EVS)           // combined edge count

typedef __attribute__((ext_vector_type(8))) short short8;
typedef __attribute__((ext_vector_type(4))) float f32x4;

__device__ __forceinline__ unsigned short f2bf(float x) {
  unsigned u = __float_as_uint(x);
  unsigned r = (u + 0x7FFFu + ((u >> 16) & 1u)) >> 16;   // RNE
  return (unsigned short)r;
}

// ---------------- Stage 0: all projections in one kernel ----------------
template<int F>
__device__ __forceinline__ void proj_body(const float* __restrict__ x,
    const float* __restrict__ W, const float* __restrict__ b,
    float* __restrict__ out, int blk, int N) {
  int n = __builtin_amdgcn_readfirstlane((int)(blk * 4 + (threadIdx.x >> 6)));
  int j = threadIdx.x & 63;
  if (n >= N) return;
  const float* xr = x + (size_t)n * F;
  float acc = b[j];
  #pragma unroll
  for (int f = 0; f < F; ++f) acc = fmaf(xr[f], W[f * 64 + j], acc);
  out[(size_t)n * 64 + j] = fmaxf(acc, 0.0f);
}

__global__ __launch_bounds__(256) void proj_all_kernel(
    const float* __restrict__ x_emp, const float* __restrict__ W_emp, const float* __restrict__ b_emp, float* __restrict__ h_emp,
    const float* __restrict__ x_shift, const float* __restrict__ W_shift, const float* __restrict__ b_shift, float* __restrict__ h_sh0,
    const float* __restrict__ x_var, const float* __restrict__ W_var, const float* __restrict__ b_var, float* __restrict__ h_var) {
  int blk = blockIdx.x;
  if (blk < 750)            proj_body<32>(x_emp,   W_emp,   b_emp,   h_emp, blk,        NEMP);
  else if (blk < 750+7500)  proj_body<24>(x_shift, W_shift, b_shift, h_sh0, blk-750,    NSHIFT);
  else                      proj_body<19>(x_var,   W_var,   b_var,   h_var, blk-8250,   NVAR);
}

// ---------------- prep: qkfold x2 + fuseW bf16 fragment pre-swizzle ----------------
__device__ __forceinline__ void qkfold_body(const float* __restrict__ qW,
    const float* __restrict__ kW, float* __restrict__ W2) {
  int j = threadIdx.x & 63;
  int fq = threadIdx.x >> 6;
  for (int ff = 0; ff < 16; ++ff) {
    int f = fq * 16 + ff;
    float acc = 0.0f;
    #pragma unroll
    for (int d = 0; d < 64; ++d) acc = fmaf(qW[j * 64 + d], kW[f * 64 + d], acc);
    W2[f * 64 + j] = 0.125f * acc;
  }
}

__global__ __launch_bounds__(256) void small_prep_kernel(
    const float* __restrict__ qWe, const float* __restrict__ kWe,
    const float* __restrict__ qWs, const float* __restrict__ kWs,
    const float* __restrict__ fuseW,
    float* __restrict__ W2e, float* __restrict__ W2s,
    unsigned short* __restrict__ fuseWb) {
  if (blockIdx.x == 0) { qkfold_body(qWe, kWe, W2e); return; }
  if (blockIdx.x == 1) { qkfold_body(qWs, kWs, W2s); return; }
  // fragment order: idx = ((nt*6 + kb)*64 + lane)*8 + i ; k = kb*32 + (lane>>4)*8 + i ; n = nt*16 + (lane&15)
  for (int linear = threadIdx.x; linear < 192 * 64; linear += 256) {
    int i    = linear & 7;
    int lane = (linear >> 3) & 63;
    int g    = linear >> 9;          // nt*6 + kb
    int kb   = g % 6, nt = g / 6;
    int k = kb * 32 + (lane >> 4) * 8 + i;
    int n = nt * 16 + (lane & 15);
    fuseWb[linear] = f2bf(fuseW[k * 64 + n]);
  }
}

// ---------------- merged linear64: 4 jobs ----------------
__global__ __launch_bounds__(256) void linear_all_kernel(
    const float* __restrict__ h_emp, const float* __restrict__ h_sh1,
    const float* __restrict__ injW_e, const float* __restrict__ injb_e, const float* __restrict__ W2e,
    const float* __restrict__ injW_s, const float* __restrict__ injb_s, const float* __restrict__ W2s,
    float* __restrict__ Vpe, float* __restrict__ K2e,
    float* __restrict__ Vps, float* __restrict__ K2s) {
  int b = blockIdx.x;
  const float *h, *W, *bias; float* out; int nb, N;
  if (b < 750)        { h = h_emp; W = injW_e; bias = injb_e; out = Vpe; nb = b;        N = NEMP; }
  else if (b < 1500)  { h = h_emp; W = W2e;    bias = nullptr; out = K2e; nb = b - 750; N = NEMP; }
  else if (b < 9000)  { h = h_sh1; W = injW_s; bias = injb_s; out = Vps; nb = b - 1500; N = NSHIFT; }
  else                { h = h_sh1; W = W2s;    bias = nullptr; out = K2s; nb = b - 9000; N = NSHIFT; }
  int n = __builtin_amdgcn_readfirstlane((int)(nb * 4 + (threadIdx.x >> 6)));
  int j = threadIdx.x & 63;
  if (n >= N) return;
  const float* hr = h + (size_t)n * 64;
  float acc = bias ? bias[j] : 0.0f;
  #pragma unroll
  for (int f = 0; f < 64; ++f) acc = fmaf(hr[f], W[f * 64 + j], acc);
  out[(size_t)n * 64 + j] = acc;
}

// ---------------- Stage 1a: X = h_shift @ gat_W ; a_s/a_d per (node, head) ----------------
__global__ __launch_bounds__(256) void gat_x_kernel(const float* __restrict__ h,
    const float* __restrict__ gat_W, const float* __restrict__ att_src,
    const float* __restrict__ att_dst, float* __restrict__ X,
    float* __restrict__ a_s, float* __restrict__ a_d, int N) {
  __shared__ float Wl[64 * 256];
  int c = threadIdx.x;
  for (int f = 0; f < 64; ++f) Wl[f * 256 + c] = gat_W[f * 256 + c];
  __syncthreads();
  int h4 = c >> 6, d = c & 63;
  float asrc = att_src[h4 * 64 + d], adst = att_dst[h4 * 64 + d];
  int n0 = blockIdx.x * 8;
  for (int k = 0; k < 8; ++k) {
    int n = n0 + k;
    if (n >= N) break;
    const float* hr = h + (size_t)n * 64;
    float acc = 0.0f;
    #pragma unroll
    for (int f = 0; f < 64; ++f) acc = fmaf(hr[f], Wl[f * 256 + c], acc);
    X[(size_t)n * 256 + c] = acc;
    float ps = acc * asrc, pd = acc * adst;
    #pragma unroll
    for (int o = 32; o > 0; o >>= 1) { ps += __shfl_xor(ps, o); pd += __shfl_xor(pd, o); }
    if (d == 0) { a_s[n * 4 + h4] = ps; a_d[n * 4 + h4] = pd; }
  }
}

// ---------------- combined CSR build over all 3 edge sets ----------------
__global__ __launch_bounds__(256) void count_all_kernel(
    const int* __restrict__ sd_dst, const int* __restrict__ ve_var,
    const int* __restrict__ vs_var, int* __restrict__ cnt) {
  for (int i = blockIdx.x * 256 + threadIdx.x; i < ET_ALL; i += gridDim.x * 256) {
    int key;
    if (i < ESD)            key = sd_dst[i];
    else if (i < ESD + EVE) key = NSHIFT + ve_var[i - ESD];
    else                    key = NSHIFT + NVAR + vs_var[i - ESD - EVE];
    atomicAdd(&cnt[key], 1);
  }
}

__global__ __launch_bounds__(256) void scan_phase1(const int* __restrict__ cnt, int N,
                                                   int* __restrict__ partial) {
  __shared__ int sd[256];
  int t = threadIdx.x;
  int base = blockIdx.x * 1024 + t * 4;
  int s = 0;
  #pragma unroll
  for (int k = 0; k < 4; ++k) { int i = base + k; if (i < N) s += cnt[i]; }
  sd[t] = s; __syncthreads();
  for (int o = 128; o > 0; o >>= 1) { if (t < o) sd[t] += sd[t + o]; __syncthreads(); }
  if (t == 0) partial[blockIdx.x] = sd[0];
}

__global__ __launch_bounds__(1024) void scan_phase2(int* __restrict__ partial, int B) {
  __shared__ int sd[1024];
  int t = threadIdx.x;
  int v = (t < B) ? partial[t] : 0;
  sd[t] = v; __syncthreads();
  for (int o = 1; o < 1024; o <<= 1) {
    int add = (t >= o) ? sd[t - o] : 0;
    __syncthreads();
    sd[t] += add;
    __syncthreads();
  }
  if (t < B) partial[t] = sd[t] - v;   // exclusive
}

__global__ __launch_bounds__(256) void scan_phase3(int* __restrict__ cnt, int N,
    const int* __restrict__ partial, int* __restrict__ row) {
  __shared__ int sd[256];
  int t = threadIdx.x;
  int base = blockIdx.x * 1024 + t * 4;
  int v[4]; int s = 0;
  #pragma unroll
  for (int k = 0; k < 4; ++k) { int i = base + k; v[k] = (i < N) ? cnt[i] : 0; s += v[k]; }
  sd[t] = s; __syncthreads();
  for (int o = 1; o < 256; o <<= 1) {
    int add = (t >= o) ? sd[t - o] : 0;
    __syncthreads();
    sd[t] += add;
    __syncthreads();
  }
  int run = partial[blockIdx.x] + sd[t] - s;
  #pragma unroll
  for (int k = 0; k < 4; ++k) {
    int i = base + k;
    if (i < N) {
      row[i] = run; cnt[i] = run; run += v[k];
      if (i == N - 1) row[N] = run;
    }
  }
}

__global__ __launch_bounds__(256) void fill_all_kernel(
    const int* __restrict__ sd_dst, const int* __restrict__ sd_src,
    const int* __restrict__ ve_var, const int* __restrict__ ve_emp,
    const int* __restrict__ vs_var, const int* __restrict__ vs_shift,
    int* __restrict__ cursor, int* __restrict__ elist) {
  for (int i = blockIdx.x * 256 + threadIdx.x; i < ET_ALL; i += gridDim.x * 256) {
    int key, val;
    if (i < ESD)            { key = sd_dst[i];                          val = sd_src[i]; }
    else if (i < ESD + EVE) { int j = i - ESD;       key = NSHIFT + ve_var[j];        val = ve_emp[j]; }
    else                    { int j = i - ESD - EVE; key = NSHIFT + NVAR + vs_var[j]; val = vs_shift[j]; }
    int pos = atomicAdd(&cursor[key], 1);
    elist[pos] = val;
  }
}

// ---------------- Stage 1b: GAT aggregate (wave per dst node; 16-lane subgroup = head) ----
__global__ __launch_bounds__(256) void gat_aggr_kernel(const float* __restrict__ X,
    const float* __restrict__ a_s, const float* __restrict__ a_d,
    const int* __restrict__ row, const int* __restrict__ elist,
    const float* __restrict__ gat_b, const float* __restrict__ h0,
    float* __restrict__ h1, int N) {
  int n = __builtin_amdgcn_readfirstlane((int)(blockIdx.x * 4 + (threadIdx.x >> 6)));
  int l = threadIdx.x & 63;
  if (n >= N) return;
  int g = l >> 4, sl = l & 15;
  int beg = row[n], end = row[n + 1];
  float ad = a_d[n * 4 + g];
  float4 acc = make_float4(0.f, 0.f, 0.f, 0.f);
  float z = 0.0f;
  for (int p = beg; p < end; ++p) {
    int s = elist[p];
    float e = a_s[s * 4 + g] + ad;
    e = e > 0.0f ? e : 0.2f * e;
    float ex = __expf(e);
    z += ex;
    const float4 x4 = *(const float4*)(X + (size_t)s * 256 + g * 64 + sl * 4);
    acc.x = fmaf(ex, x4.x, acc.x); acc.y = fmaf(ex, x4.y, acc.y);
    acc.z = fmaf(ex, x4.z, acc.z); acc.w = fmaf(ex, x4.w, acc.w);
  }
  float inv = 0.25f / fmaxf(z, 1e-16f);
  float4 v = make_float4(acc.x * inv, acc.y * inv, acc.z * inv, acc.w * inv);
  v.x += __shfl_xor(v.x, 16); v.x += __shfl_xor(v.x, 32);
  v.y += __shfl_xor(v.y, 16); v.y += __shfl_xor(v.y, 32);
  v.z += __shfl_xor(v.z, 16); v.z += __shfl_xor(v.z, 32);
  v.w += __shfl_xor(v.w, 16); v.w += __shfl_xor(v.w, 32);
  if (g == 0) {
    const float4 b4 = *(const float4*)(gat_b + sl * 4);
    const float4 h04 = *(const float4*)(h0 + (size_t)n * 64 + sl * 4);
    float4 o;
    o.x = fmaxf(v.x + b4.x, 0.0f) + h04.x;
    o.y = fmaxf(v.y + b4.y, 0.0f) + h04.y;
    o.z = fmaxf(v.z + b4.z, 0.0f) + h04.z;
    o.w = fmaxf(v.w + b4.w, 0.0f) + h04.w;
    *(float4*)(h1 + (size_t)n * 64 + sl * 4) = o;
  }
}

// ---------------- Stage 2+3 fused: inject x2 + MFMA fuse matmul + L2 norm ----------
__global__ __launch_bounds__(512) void stage2_kernel(
    const float* __restrict__ h_var,
    const float* __restrict__ K2e, const float* __restrict__ Vpe,
    const int* __restrict__ ve_row, const int* __restrict__ ve_src,
    const float* __restrict__ K2s, const float* __restrict__ Vps,
    const int* __restrict__ vs_row, const int* __restrict__ vs_src,
    const unsigned short* __restrict__ fuseWb, const float* __restrict__ fuseb,
    float* __restrict__ out, int N) {
  __shared__ float fT[192][65];   // [feature][node-col]
  __shared__ float ssq2[64][2];
  int tid = threadIdx.x;
  int lane = tid & 63;
  int w = __builtin_amdgcn_readfirstlane((int)(tid >> 6));   // 0..7
  int g = lane >> 4, sl = lane & 15;
  int blockStart = blockIdx.x * 64;

  // ---- Phase A: injections; wave w owns node-cols w*8 .. w*8+7 ----
  for (int k = 0; k < 2; ++k) {
    int c = w * 8 + k * 4 + g;
    int n = blockStart + c;
    bool act = (n < N);
    float4 hv = act ? *(const float4*)(h_var + (size_t)n * 64 + sl * 4)
                    : make_float4(0.f, 0.f, 0.f, 0.f);
    fT[sl * 4 + 0][c] = hv.x; fT[sl * 4 + 1][c] = hv.y;
    fT[sl * 4 + 2][c] = hv.z; fT[sl * 4 + 3][c] = hv.w;

    #pragma unroll
    for (int which = 0; which < 2; ++which) {
      const int*   rowp = which ? vs_row : ve_row;
      const int*   srcp = which ? vs_src : ve_src;
      const float* K2   = which ? K2s : K2e;
      const float* Vp   = which ? Vps : Vpe;
      int outBase = which ? 128 : 64;
      int b = 0, e = 0;
      if (act) { b = rowp[n]; e = rowp[n + 1]; }
      float4 acc = make_float4(0.f, 0.f, 0.f, 0.f);
      float z = 0.0f;
      for (int p = b; p < e; ++p) {
        int s = srcp[p];
        const float4 k4 = *(const float4*)(K2 + (size_t)s * 64 + sl * 4);
        float part = hv.x * k4.x + hv.y * k4.y + hv.z * k4.z + hv.w * k4.w;
        part += __shfl_xor(part, 1); part += __shfl_xor(part, 2);
        part += __shfl_xor(part, 4); part += __shfl_xor(part, 8);
        float ex = __expf(part);
        z += ex;
        const float4 v4 = *(const float4*)(Vp + (size_t)s * 64 + sl * 4);
        acc.x = fmaf(ex, v4.x, acc.x); acc.y = fmaf(ex, v4.y, acc.y);
        acc.z = fmaf(ex, v4.z, acc.z); acc.w = fmaf(ex, v4.w, acc.w);
      }
      float inv = (e > b) ? 1.0f / fmaxf(z, 1e-9f) : 0.0f;
      fT[outBase + sl * 4 + 0][c] = acc.x * inv;
      fT[outBase + sl * 4 + 1][c] = acc.y * inv;
      fT[outBase + sl * 4 + 2][c] = acc.z * inv;
      fT[outBase + sl * 4 + 3][c] = acc.w * inv;
    }
  }
  __syncthreads();

  // ---- Phase B: fuse matmul via bf16 MFMA 16x16x32 ----
  // wave w: mtile = w>>1 ; ntiles = (w&1)*2 + {0,1}
  {
    int mtile = w >> 1;
    int row16 = lane & 15, blk = lane >> 4;
    int mrow = mtile * 16 + row16;            // node col in fT for A frag
    float nodeSS[4] = {0.f, 0.f, 0.f, 0.f};
    #pragma unroll
    for (int t = 0; t < 2; ++t) {
      int ntile = (w & 1) * 2 + t;
      f32x4 acc = {0.f, 0.f, 0.f, 0.f};
      #pragma unroll
      for (int kb = 0; kb < 6; ++kb) {
        short8 a;
        #pragma unroll
        for (int i = 0; i < 8; ++i)
          a[i] = (short)f2bf(fT[kb * 32 + blk * 8 + i][mrow]);
        short8 bfr = *(const short8*)(fuseWb + (((ntile * 6 + kb) * 64 + lane) << 3));
        acc = __builtin_amdgcn_mfma_f32_16x16x32_bf16(a, bfr, acc, 0, 0, 0);
      }
      float fb = fuseb[ntile * 16 + row16];
      #pragma unroll
      for (int r = 0; r < 4; ++r) {
        float v = fmaxf(acc[r] + fb, 0.0f);
        float vv = v * v;
        vv += __shfl_xor(vv, 1); vv += __shfl_xor(vv, 2);
        vv += __shfl_xor(vv, 4); vv += __shfl_xor(vv, 8);
        nodeSS[r] += vv;          // valid on lanes with row16==0
      }
    }
    if (row16 == 0) {
      #pragma unroll
      for (int r = 0; r < 4; ++r)
        ssq2[mtile * 16 + blk * 4 + r][w & 1] = nodeSS[r];
    }
  }
  __syncthreads();
  if (tid < 64) {
    int n = blockStart + tid;
    if (n < N) out[n] = sqrtf(ssq2[tid][0] + ssq2[tid][1]);
  }
}

// ---------------- host ----------------
extern "C" void kernel_launch(void* const* d_in, const int* in_sizes, int n_in,
                              void* d_out, int out_size, void* d_ws, size_t ws_size,
                              hipStream_t stream) {
  const float* x_emp   = (const float*)d_in[0];
  const float* x_shift = (const float*)d_in[1];
  const float* x_var   = (const float*)d_in[2];
  const float* W_emp   = (const float*)d_in[4];
  const float* b_emp   = (const float*)d_in[5];
  const float* W_shift = (const float*)d_in[6];
  const float* b_shift = (const float*)d_in[7];
  const float* W_var   = (const float*)d_in[8];
  const float* b_var   = (const float*)d_in[9];
  const float* gat_W   = (const float*)d_in[12];
  const float* att_s   = (const float*)d_in[13];
  const float* att_d   = (const float*)d_in[14];
  const float* gat_b   = (const float*)d_in[15];
  const float* injW_e  = (const float*)d_in[16];
  const float* injb_e  = (const float*)d_in[17];
  const float* injW_s  = (const float*)d_in[18];
  const float* injb_s  = (const float*)d_in[19];
  const float* qW_e    = (const float*)d_in[20];
  const float* kW_e    = (const float*)d_in[21];
  const float* qW_s    = (const float*)d_in[22];
  const float* kW_s    = (const float*)d_in[23];
  const float* fuseW   = (const float*)d_in[24];
  const float* fuseb   = (const float*)d_in[25];
  const int* sd_src  = (const int*)d_in[26];
  const int* sd_dst  = (const int*)d_in[27];
  const int* ve_var  = (const int*)d_in[28];
  const int* ve_emp  = (const int*)d_in[29];
  const int* vs_var  = (const int*)d_in[30];
  const int* vs_shift= (const int*)d_in[31];
  float* out = (float*)d_out;

  char* base = (char*)d_ws;
  size_t off = 0;
  auto A = [&](size_t nbytes) -> void* {
    void* r = base + off;
    off = (off + nbytes + 255) & ~(size_t)255;
    return r;
  };
  float* h_emp = (float*)A((size_t)NEMP * 64 * 4);
  float* h_sh0 = (float*)A((size_t)NSHIFT * 64 * 4);
  float* h_sh1 = (float*)A((size_t)NSHIFT * 64 * 4);
  float* h_var = (float*)A((size_t)NVAR * 64 * 4);
  float* Xg    = (float*)A((size_t)NSHIFT * 256 * 4);
  float* a_s   = (float*)A((size_t)NSHIFT * 4 * 4);
  float* a_d   = (float*)A((size_t)NSHIFT * 4 * 4);
  float* Vpe   = (float*)A((size_t)NEMP * 64 * 4);
  float* K2e   = (float*)A((size_t)NEMP * 64 * 4);
  float* Vps   = (float*)A((size_t)NSHIFT * 64 * 4);
  float* K2s   = (float*)A((size_t)NSHIFT * 64 * 4);
  float* W2e   = (float*)A((size_t)64 * 64 * 4);
  float* W2s   = (float*)A((size_t)64 * 64 * 4);
  unsigned short* fuseWb = (unsigned short*)A((size_t)192 * 64 * 2);
  int* cnt     = (int*)A((size_t)NT_CNT * 4);
  int* row_all = (int*)A((size_t)(NT_CNT + 1) * 4);
  int* el_all  = (int*)A((size_t)ET_ALL * 4);
  int* partial = (int*)A(1024 * 4);

  hipMemsetAsync(cnt, 0, (size_t)NT_CNT * 4, stream);

  // Stage 0: all projections (h_con unused -> skipped)
  proj_all_kernel<<<750 + 7500 + 125000, 256, 0, stream>>>(
      x_emp, W_emp, b_emp, h_emp,
      x_shift, W_shift, b_shift, h_sh0,
      x_var, W_var, b_var, h_var);

  // combined CSR over {sd, ve, vs}
  count_all_kernel<<<2048, 256, 0, stream>>>(sd_dst, ve_var, vs_var, cnt);
  int B = (NT_CNT + 1023) / 1024;   // 1006
  scan_phase1<<<B, 256, 0, stream>>>(cnt, NT_CNT, partial);
  scan_phase2<<<1, 1024, 0, stream>>>(partial, B);
  scan_phase3<<<B, 256, 0, stream>>>(cnt, NT_CNT, partial, row_all);
  fill_all_kernel<<<2048, 256, 0, stream>>>(sd_dst, sd_src, ve_var, ve_emp,
                                            vs_var, vs_shift, cnt, el_all);

  // Stage 1: GAT
  gat_x_kernel<<<(NSHIFT + 7) / 8, 256, 0, stream>>>(h_sh0, gat_W, att_s, att_d,
                                                     Xg, a_s, a_d, NSHIFT);
  gat_aggr_kernel<<<(NSHIFT + 3) / 4, 256, 0, stream>>>(Xg, a_s, a_d, row_all, el_all,
                                                        gat_b, h_sh0, h_sh1, NSHIFT);

  // Stage 2 prep
  small_prep_kernel<<<3, 256, 0, stream>>>(qW_e, kW_e, qW_s, kW_s, fuseW, W2e, W2s, fuseWb);
  linear_all_kernel<<<16500, 256, 0, stream>>>(h_emp, h_sh1,
      injW_e, injb_e, W2e, injW_s, injb_s, W2s, Vpe, K2e, Vps, K2s);

  // Stage 2+3 fused
  stage2_kernel<<<(NVAR + 63) / 64, 512, 0, stream>>>(h_var,
      K2e, Vpe, row_all + NSHIFT, el_all,
      K2s, Vps, row_all + NSHIFT + NVAR, el_all,
      fuseWb, fuseb, out, NVAR);
}

// Round 4
// 694.514 us; speedup vs baseline: 4.3304x; 1.1216x over previous
//
#include <hip/hip_runtime.h>
#include <math.h>

#define NEMP   3000
#define NSHIFT 30000
#define NVAR   500000
#define ESD    960000
#define EVE    500000
#define EVS    500000
#define NT_CNT (NSHIFT + NVAR + NVAR)      // combined segment count = 1,030,000
#define ET_ALL (ESD + EVE + EVS)           // combined edge count   = 1,960,000

// ---- binned CSR build geometry ----
#define NBUCK  959        // 469 sd buckets (64 keys) + 245 ve + 245 vs (2048 keys)
#define NBLK0  256        // bin pass blocks
#define CHUNK  7657       // ceil(ET_ALL / NBLK0)
#define SSTRIDE 7664      // staging stride per block (>= CHUNK, 8-aligned)

typedef __attribute__((ext_vector_type(8))) short short8;
typedef __attribute__((ext_vector_type(4))) float f32x4;

__device__ __forceinline__ unsigned short f2bf(float x) {
  unsigned u = __float_as_uint(x);
  unsigned r = (u + 0x7FFFu + ((u >> 16) & 1u)) >> 16;   // RNE
  return (unsigned short)r;
}

// ---------------- Stage 0: all projections in one kernel ----------------
template<int F>
__device__ __forceinline__ void proj_body(const float* __restrict__ x,
    const float* __restrict__ W, const float* __restrict__ b,
    float* __restrict__ out, int blk, int N) {
  int n = __builtin_amdgcn_readfirstlane((int)(blk * 4 + (threadIdx.x >> 6)));
  int j = threadIdx.x & 63;
  if (n >= N) return;
  const float* xr = x + (size_t)n * F;
  float acc = b[j];
  #pragma unroll
  for (int f = 0; f < F; ++f) acc = fmaf(xr[f], W[f * 64 + j], acc);
  out[(size_t)n * 64 + j] = fmaxf(acc, 0.0f);
}

__global__ __launch_bounds__(256) void proj_all_kernel(
    const float* __restrict__ x_emp, const float* __restrict__ W_emp, const float* __restrict__ b_emp, float* __restrict__ h_emp,
    const float* __restrict__ x_shift, const float* __restrict__ W_shift, const float* __restrict__ b_shift, float* __restrict__ h_sh0,
    const float* __restrict__ x_var, const float* __restrict__ W_var, const float* __restrict__ b_var, float* __restrict__ h_var) {
  int blk = blockIdx.x;
  if (blk < 750)            proj_body<32>(x_emp,   W_emp,   b_emp,   h_emp, blk,        NEMP);
  else if (blk < 750+7500)  proj_body<24>(x_shift, W_shift, b_shift, h_sh0, blk-750,    NSHIFT);
  else                      proj_body<19>(x_var,   W_var,   b_var,   h_var, blk-8250,   NVAR);
}

// ---------------- prep: qkfold x2 + fuseW bf16 fragment pre-swizzle ----------------
__device__ __forceinline__ void qkfold_body(const float* __restrict__ qW,
    const float* __restrict__ kW, float* __restrict__ W2) {
  int j = threadIdx.x & 63;
  int fq = threadIdx.x >> 6;
  for (int ff = 0; ff < 16; ++ff) {
    int f = fq * 16 + ff;
    float acc = 0.0f;
    #pragma unroll
    for (int d = 0; d < 64; ++d) acc = fmaf(qW[j * 64 + d], kW[f * 64 + d], acc);
    W2[f * 64 + j] = 0.125f * acc;
  }
}

__global__ __launch_bounds__(256) void small_prep_kernel(
    const float* __restrict__ qWe, const float* __restrict__ kWe,
    const float* __restrict__ qWs, const float* __restrict__ kWs,
    const float* __restrict__ fuseW,
    float* __restrict__ W2e, float* __restrict__ W2s,
    unsigned short* __restrict__ fuseWb) {
  if (blockIdx.x == 0) { qkfold_body(qWe, kWe, W2e); return; }
  if (blockIdx.x == 1) { qkfold_body(qWs, kWs, W2s); return; }
  // fragment order: idx = ((nt*6 + kb)*64 + lane)*8 + i ; k = kb*32 + (lane>>4)*8 + i ; n = nt*16 + (lane&15)
  for (int linear = threadIdx.x; linear < 192 * 64; linear += 256) {
    int i    = linear & 7;
    int lane = (linear >> 3) & 63;
    int g    = linear >> 9;          // nt*6 + kb
    int kb   = g % 6, nt = g / 6;
    int k = kb * 32 + (lane >> 4) * 8 + i;
    int n = nt * 16 + (lane & 15);
    fuseWb[linear] = f2bf(fuseW[k * 64 + n]);
  }
}

// ---------------- merged linear64: 4 jobs ----------------
__global__ __launch_bounds__(256) void linear_all_kernel(
    const float* __restrict__ h_emp, const float* __restrict__ h_sh1,
    const float* __restrict__ injW_e, const float* __restrict__ injb_e, const float* __restrict__ W2e,
    const float* __restrict__ injW_s, const float* __restrict__ injb_s, const float* __restrict__ W2s,
    float* __restrict__ Vpe, float* __restrict__ K2e,
    float* __restrict__ Vps, float* __restrict__ K2s) {
  int b = blockIdx.x;
  const float *h, *W, *bias; float* out; int nb, N;
  if (b < 750)        { h = h_emp; W = injW_e; bias = injb_e; out = Vpe; nb = b;        N = NEMP; }
  else if (b < 1500)  { h = h_emp; W = W2e;    bias = nullptr; out = K2e; nb = b - 750; N = NEMP; }
  else if (b < 9000)  { h = h_sh1; W = injW_s; bias = injb_s; out = Vps; nb = b - 1500; N = NSHIFT; }
  else                { h = h_sh1; W = W2s;    bias = nullptr; out = K2s; nb = b - 9000; N = NSHIFT; }
  int n = __builtin_amdgcn_readfirstlane((int)(nb * 4 + (threadIdx.x >> 6)));
  int j = threadIdx.x & 63;
  if (n >= N) return;
  const float* hr = h + (size_t)n * 64;
  float acc = bias ? bias[j] : 0.0f;
  #pragma unroll
  for (int f = 0; f < 64; ++f) acc = fmaf(hr[f], W[f * 64 + j], acc);
  out[(size_t)n * 64 + j] = acc;
}

// ---------------- Stage 1a: X = h_shift @ gat_W ; a_s/a_d per (node, head) ----------------
__global__ __launch_bounds__(256) void gat_x_kernel(const float* __restrict__ h,
    const float* __restrict__ gat_W, const float* __restrict__ att_src,
    const float* __restrict__ att_dst, float* __restrict__ X,
    float* __restrict__ a_s, float* __restrict__ a_d, int N) {
  __shared__ float Wl[64 * 256];
  int c = threadIdx.x;
  for (int f = 0; f < 64; ++f) Wl[f * 256 + c] = gat_W[f * 256 + c];
  __syncthreads();
  int h4 = c >> 6, d = c & 63;
  float asrc = att_src[h4 * 64 + d], adst = att_dst[h4 * 64 + d];
  int n0 = blockIdx.x * 8;
  for (int k = 0; k < 8; ++k) {
    int n = n0 + k;
    if (n >= N) break;
    const float* hr = h + (size_t)n * 64;
    float acc = 0.0f;
    #pragma unroll
    for (int f = 0; f < 64; ++f) acc = fmaf(hr[f], Wl[f * 256 + c], acc);
    X[(size_t)n * 256 + c] = acc;
    float ps = acc * asrc, pd = acc * adst;
    #pragma unroll
    for (int o = 32; o > 0; o >>= 1) { ps += __shfl_xor(ps, o); pd += __shfl_xor(pd, o); }
    if (d == 0) { a_s[n * 4 + h4] = ps; a_d[n * 4 + h4] = pd; }
  }
}

// ---------------- binned CSR build ----------------
// decode edge i -> (bucket, local key, val)
__device__ __forceinline__ void edge_decode(int i,
    const int* __restrict__ sd_dst, const int* __restrict__ sd_src,
    const int* __restrict__ ve_var, const int* __restrict__ ve_emp,
    const int* __restrict__ vs_var, const int* __restrict__ vs_shift,
    int& b, int& lk, int& val) {
  if (i < ESD)            { int d = sd_dst[i]; b = d >> 6; lk = d & 63; val = sd_src[i]; }
  else if (i < ESD + EVE) { int j = i - ESD; int d = ve_var[j]; b = 469 + (d >> 11); lk = d & 2047; val = ve_emp[j]; }
  else                    { int j = i - ESD - EVE; int d = vs_var[j]; b = 714 + (d >> 11); lk = d & 2047; val = vs_shift[j]; }
}

// pass 0: per-block binning into private staging; table[b*NBLK0+blk] = seg start
__global__ __launch_bounds__(256) void bin_kernel(
    const int* __restrict__ sd_dst, const int* __restrict__ sd_src,
    const int* __restrict__ ve_var, const int* __restrict__ ve_emp,
    const int* __restrict__ vs_var, const int* __restrict__ vs_shift,
    uint2* __restrict__ staging, int* __restrict__ table) {
  __shared__ int hist[NBUCK];
  __shared__ int sums[256];
  int t = threadIdx.x, blk = blockIdx.x;
  int e0 = blk * CHUNK;
  int e1 = min(e0 + CHUNK, ET_ALL);
  int sbase = blk * SSTRIDE;
  for (int i = t; i < NBUCK; i += 256) hist[i] = 0;
  __syncthreads();
  for (int i = e0 + t; i < e1; i += 256) {
    int b, lk, val;
    edge_decode(i, sd_dst, sd_src, ve_var, ve_emp, vs_var, vs_shift, b, lk, val);
    atomicAdd(&hist[b], 1);
  }
  __syncthreads();
  // exclusive scan of hist[0..NBUCK) in place; write table
  int base = t * 4, v[4], s = 0;
  #pragma unroll
  for (int k = 0; k < 4; ++k) { int i = base + k; v[k] = (i < NBUCK) ? hist[i] : 0; s += v[k]; }
  sums[t] = s; __syncthreads();
  for (int o = 1; o < 256; o <<= 1) {
    int add = (t >= o) ? sums[t - o] : 0;
    __syncthreads(); sums[t] += add; __syncthreads();
  }
  int run = sums[t] - s;
  #pragma unroll
  for (int k = 0; k < 4; ++k) {
    int i = base + k;
    if (i < NBUCK) { hist[i] = run; table[i * NBLK0 + blk] = sbase + run; run += v[k]; }
  }
  if (t == 0) table[NBUCK * NBLK0 + blk] = sbase + (e1 - e0);
  __syncthreads();
  // place edges into private staging (hist now = running cursors)
  for (int i = e0 + t; i < e1; i += 256) {
    int b, lk, val;
    edge_decode(i, sd_dst, sd_src, ve_var, ve_emp, vs_var, vs_shift, b, lk, val);
    int pos = sbase + atomicAdd(&hist[b], 1);
    staging[pos] = make_uint2((unsigned)lk, (unsigned)val);
  }
}

// pass 1: bucket totals -> exclusive scan -> bucket starts
__global__ __launch_bounds__(1024) void bstart_kernel(const int* __restrict__ table,
                                                      int* __restrict__ bstart) {
  __shared__ int histL[NBUCK];
  __shared__ int sd[1024];
  int t = threadIdx.x;
  for (int i = t; i < NBUCK; i += 1024) histL[i] = 0;
  __syncthreads();
  for (int idx = t; idx < NBUCK * NBLK0; idx += 1024) {
    int len = table[idx + NBLK0] - table[idx];
    if (len) atomicAdd(&histL[idx >> 8], len);   // NBLK0 == 256
  }
  __syncthreads();
  int v = (t < NBUCK) ? histL[t] : 0;
  sd[t] = v; __syncthreads();
  for (int o = 1; o < 1024; o <<= 1) {
    int add = (t >= o) ? sd[t - o] : 0;
    __syncthreads(); sd[t] += add; __syncthreads();
  }
  if (t < NBUCK) bstart[t] = sd[t] - v;
  if (t == NBUCK - 1) bstart[NBUCK] = sd[t];
}

// pass 2: one block per bucket -> row[] + elist[]
__global__ __launch_bounds__(256) void csr_build_kernel(
    const uint2* __restrict__ staging, const int* __restrict__ table,
    const int* __restrict__ bstart, int* __restrict__ row, int* __restrict__ elist) {
  __shared__ int segstart[NBLK0];
  __shared__ int cum[NBLK0];        // inclusive lens
  __shared__ int hist[2048];
  __shared__ int sums[256];
  int b = blockIdx.x, t = threadIdx.x;
  {
    int s0 = table[b * NBLK0 + t];
    int s1 = table[(b + 1) * NBLK0 + t];
    segstart[t] = s0;
    cum[t] = s1 - s0;
  }
  for (int i = t; i < 2048; i += 256) hist[i] = 0;
  __syncthreads();
  for (int o = 1; o < NBLK0; o <<= 1) {
    int add = (t >= o) ? cum[t - o] : 0;
    __syncthreads(); cum[t] += add; __syncthreads();
  }
  int total = cum[NBLK0 - 1];
  // region geometry
  int keyBase, kcount;
  if (b < 469)      { keyBase = b * 64;                     kcount = min(64,   30000  - b * 64); }
  else if (b < 714) { int lb = b - 469; keyBase = 30000  + lb * 2048; kcount = min(2048, 500000 - lb * 2048); }
  else              { int lb = b - 714; keyBase = 530000 + lb * 2048; kcount = min(2048, 500000 - lb * 2048); }
  // phase A: local-key histogram
  for (int idx = t; idx < total; idx += 256) {
    int lo = 0, hi = NBLK0 - 1;
    while (lo < hi) { int mid = (lo + hi) >> 1; if (cum[mid] > idx) hi = mid; else lo = mid + 1; }
    int off = idx - (lo ? cum[lo - 1] : 0);
    unsigned lk = staging[segstart[lo] + off].x;
    atomicAdd(&hist[lk], 1);
  }
  __syncthreads();
  // scan hist over kcount; write rows; hist becomes cursors
  int bs = bstart[b];
  int base = t * 8, v[8], s = 0;
  #pragma unroll
  for (int k = 0; k < 8; ++k) { int i = base + k; v[k] = (i < kcount) ? hist[i] : 0; s += v[k]; }
  sums[t] = s; __syncthreads();
  for (int o = 1; o < 256; o <<= 1) {
    int add = (t >= o) ? sums[t - o] : 0;
    __syncthreads(); sums[t] += add; __syncthreads();
  }
  int run = sums[t] - s;
  #pragma unroll
  for (int k = 0; k < 8; ++k) {
    int i = base + k;
    if (i < kcount) { hist[i] = run; row[keyBase + i] = bs + run; run += v[k]; }
  }
  if (b == NBUCK - 1 && t == 0) row[NT_CNT] = bstart[NBUCK];
  __syncthreads();
  // phase C: scatter vals into bucket's contiguous elist window
  for (int idx = t; idx < total; idx += 256) {
    int lo = 0, hi = NBLK0 - 1;
    while (lo < hi) { int mid = (lo + hi) >> 1; if (cum[mid] > idx) hi = mid; else lo = mid + 1; }
    int off = idx - (lo ? cum[lo - 1] : 0);
    uint2 p = staging[segstart[lo] + off];
    int pos = bs + atomicAdd(&hist[p.x], 1);
    elist[pos] = (int)p.y;
  }
}

// ---------------- Stage 1b: GAT aggregate (wave per dst node; 16-lane subgroup = head) ----
__global__ __launch_bounds__(256) void gat_aggr_kernel(const float* __restrict__ X,
    const float* __restrict__ a_s, const float* __restrict__ a_d,
    const int* __restrict__ row, const int* __restrict__ elist,
    const float* __restrict__ gat_b, const float* __restrict__ h0,
    float* __restrict__ h1, int N) {
  int n = __builtin_amdgcn_readfirstlane((int)(blockIdx.x * 4 + (threadIdx.x >> 6)));
  int l = threadIdx.x & 63;
  if (n >= N) return;
  int g = l >> 4, sl = l & 15;
  int beg = row[n], end = row[n + 1];
  float ad = a_d[n * 4 + g];
  float4 acc = make_float4(0.f, 0.f, 0.f, 0.f);
  float z = 0.0f;
  for (int p = beg; p < end; ++p) {
    int s = elist[p];
    float e = a_s[s * 4 + g] + ad;
    e = e > 0.0f ? e : 0.2f * e;
    float ex = __expf(e);
    z += ex;
    const float4 x4 = *(const float4*)(X + (size_t)s * 256 + g * 64 + sl * 4);
    acc.x = fmaf(ex, x4.x, acc.x); acc.y = fmaf(ex, x4.y, acc.y);
    acc.z = fmaf(ex, x4.z, acc.z); acc.w = fmaf(ex, x4.w, acc.w);
  }
  float inv = 0.25f / fmaxf(z, 1e-16f);
  float4 v = make_float4(acc.x * inv, acc.y * inv, acc.z * inv, acc.w * inv);
  v.x += __shfl_xor(v.x, 16); v.x += __shfl_xor(v.x, 32);
  v.y += __shfl_xor(v.y, 16); v.y += __shfl_xor(v.y, 32);
  v.z += __shfl_xor(v.z, 16); v.z += __shfl_xor(v.z, 32);
  v.w += __shfl_xor(v.w, 16); v.w += __shfl_xor(v.w, 32);
  if (g == 0) {
    const float4 b4 = *(const float4*)(gat_b + sl * 4);
    const float4 h04 = *(const float4*)(h0 + (size_t)n * 64 + sl * 4);
    float4 o;
    o.x = fmaxf(v.x + b4.x, 0.0f) + h04.x;
    o.y = fmaxf(v.y + b4.y, 0.0f) + h04.y;
    o.z = fmaxf(v.z + b4.z, 0.0f) + h04.z;
    o.w = fmaxf(v.w + b4.w, 0.0f) + h04.w;
    *(float4*)(h1 + (size_t)n * 64 + sl * 4) = o;
  }
}

// ---------------- Stage 2+3 fused: inject x2 + MFMA fuse matmul + L2 norm ----------
__global__ __launch_bounds__(512) void stage2_kernel(
    const float* __restrict__ h_var,
    const float* __restrict__ K2e, const float* __restrict__ Vpe,
    const int* __restrict__ ve_row, const int* __restrict__ ve_src,
    const float* __restrict__ K2s, const float* __restrict__ Vps,
    const int* __restrict__ vs_row, const int* __restrict__ vs_src,
    const unsigned short* __restrict__ fuseWb, const float* __restrict__ fuseb,
    float* __restrict__ out, int N) {
  __shared__ float fT[192][65];   // [feature][node-col]
  __shared__ float ssq2[64][2];
  int tid = threadIdx.x;
  int lane = tid & 63;
  int w = __builtin_amdgcn_readfirstlane((int)(tid >> 6));   // 0..7
  int g = lane >> 4, sl = lane & 15;
  int blockStart = blockIdx.x * 64;

  // ---- Phase A: injections; wave w owns node-cols w*8 .. w*8+7 ----
  for (int k = 0; k < 2; ++k) {
    int c = w * 8 + k * 4 + g;
    int n = blockStart + c;
    bool act = (n < N);
    float4 hv = act ? *(const float4*)(h_var + (size_t)n * 64 + sl * 4)
                    : make_float4(0.f, 0.f, 0.f, 0.f);
    fT[sl * 4 + 0][c] = hv.x; fT[sl * 4 + 1][c] = hv.y;
    fT[sl * 4 + 2][c] = hv.z; fT[sl * 4 + 3][c] = hv.w;

    #pragma unroll
    for (int which = 0; which < 2; ++which) {
      const int*   rowp = which ? vs_row : ve_row;
      const int*   srcp = which ? vs_src : ve_src;
      const float* K2   = which ? K2s : K2e;
      const float* Vp   = which ? Vps : Vpe;
      int outBase = which ? 128 : 64;
      int b = 0, e = 0;
      if (act) { b = rowp[n]; e = rowp[n + 1]; }
      float4 acc = make_float4(0.f, 0.f, 0.f, 0.f);
      float z = 0.0f;
      for (int p = b; p < e; ++p) {
        int s = srcp[p];
        const float4 k4 = *(const float4*)(K2 + (size_t)s * 64 + sl * 4);
        float part = hv.x * k4.x + hv.y * k4.y + hv.z * k4.z + hv.w * k4.w;
        part += __shfl_xor(part, 1); part += __shfl_xor(part, 2);
        part += __shfl_xor(part, 4); part += __shfl_xor(part, 8);
        float ex = __expf(part);
        z += ex;
        const float4 v4 = *(const float4*)(Vp + (size_t)s * 64 + sl * 4);
        acc.x = fmaf(ex, v4.x, acc.x); acc.y = fmaf(ex, v4.y, acc.y);
        acc.z = fmaf(ex, v4.z, acc.z); acc.w = fmaf(ex, v4.w, acc.w);
      }
      float inv = (e > b) ? 1.0f / fmaxf(z, 1e-9f) : 0.0f;
      fT[outBase + sl * 4 + 0][c] = acc.x * inv;
      fT[outBase + sl * 4 + 1][c] = acc.y * inv;
      fT[outBase + sl * 4 + 2][c] = acc.z * inv;
      fT[outBase + sl * 4 + 3][c] = acc.w * inv;
    }
  }
  __syncthreads();

  // ---- Phase B: fuse matmul via bf16 MFMA 16x16x32 ----
  {
    int mtile = w >> 1;
    int row16 = lane & 15, blk = lane >> 4;
    int mrow = mtile * 16 + row16;            // node col in fT for A frag
    float nodeSS[4] = {0.f, 0.f, 0.f, 0.f};
    #pragma unroll
    for (int t = 0; t < 2; ++t) {
      int ntile = (w & 1) * 2 + t;
      f32x4 acc = {0.f, 0.f, 0.f, 0.f};
      #pragma unroll
      for (int kb = 0; kb < 6; ++kb) {
        short8 a;
        #pragma unroll
        for (int i = 0; i < 8; ++i)
          a[i] = (short)f2bf(fT[kb * 32 + blk * 8 + i][mrow]);
        short8 bfr = *(const short8*)(fuseWb + (((ntile * 6 + kb) * 64 + lane) << 3));
        acc = __builtin_amdgcn_mfma_f32_16x16x32_bf16(a, bfr, acc, 0, 0, 0);
      }
      float fb = fuseb[ntile * 16 + row16];
      #pragma unroll
      for (int r = 0; r < 4; ++r) {
        float v = fmaxf(acc[r] + fb, 0.0f);
        float vv = v * v;
        vv += __shfl_xor(vv, 1); vv += __shfl_xor(vv, 2);
        vv += __shfl_xor(vv, 4); vv += __shfl_xor(vv, 8);
        nodeSS[r] += vv;          // valid on lanes with row16==0
      }
    }
    if (row16 == 0) {
      #pragma unroll
      for (int r = 0; r < 4; ++r)
        ssq2[mtile * 16 + blk * 4 + r][w & 1] = nodeSS[r];
    }
  }
  __syncthreads();
  if (tid < 64) {
    int n = blockStart + tid;
    if (n < N) out[n] = sqrtf(ssq2[tid][0] + ssq2[tid][1]);
  }
}

// ---------------- host ----------------
extern "C" void kernel_launch(void* const* d_in, const int* in_sizes, int n_in,
                              void* d_out, int out_size, void* d_ws, size_t ws_size,
                              hipStream_t stream) {
  const float* x_emp   = (const float*)d_in[0];
  const float* x_shift = (const float*)d_in[1];
  const float* x_var   = (const float*)d_in[2];
  const float* W_emp   = (const float*)d_in[4];
  const float* b_emp   = (const float*)d_in[5];
  const float* W_shift = (const float*)d_in[6];
  const float* b_shift = (const float*)d_in[7];
  const float* W_var   = (const float*)d_in[8];
  const float* b_var   = (const float*)d_in[9];
  const float* gat_W   = (const float*)d_in[12];
  const float* att_s   = (const float*)d_in[13];
  const float* att_d   = (const float*)d_in[14];
  const float* gat_b   = (const float*)d_in[15];
  const float* injW_e  = (const float*)d_in[16];
  const float* injb_e  = (const float*)d_in[17];
  const float* injW_s  = (const float*)d_in[18];
  const float* injb_s  = (const float*)d_in[19];
  const float* qW_e    = (const float*)d_in[20];
  const float* kW_e    = (const float*)d_in[21];
  const float* qW_s    = (const float*)d_in[22];
  const float* kW_s    = (const float*)d_in[23];
  const float* fuseW   = (const float*)d_in[24];
  const float* fuseb   = (const float*)d_in[25];
  const int* sd_src  = (const int*)d_in[26];
  const int* sd_dst  = (const int*)d_in[27];
  const int* ve_var  = (const int*)d_in[28];
  const int* ve_emp  = (const int*)d_in[29];
  const int* vs_var  = (const int*)d_in[30];
  const int* vs_shift= (const int*)d_in[31];
  float* out = (float*)d_out;

  char* base = (char*)d_ws;
  size_t off = 0;
  auto A = [&](size_t nbytes) -> void* {
    void* r = base + off;
    off = (off + nbytes + 255) & ~(size_t)255;
    return r;
  };
  float* h_emp = (float*)A((size_t)NEMP * 64 * 4);
  float* h_sh0 = (float*)A((size_t)NSHIFT * 64 * 4);
  float* h_sh1 = (float*)A((size_t)NSHIFT * 64 * 4);
  float* h_var = (float*)A((size_t)NVAR * 64 * 4);
  float* Xg    = (float*)A((size_t)NSHIFT * 256 * 4);
  float* a_s   = (float*)A((size_t)NSHIFT * 4 * 4);
  float* a_d   = (float*)A((size_t)NSHIFT * 4 * 4);
  float* Vpe   = (float*)A((size_t)NEMP * 64 * 4);
  float* K2e   = (float*)A((size_t)NEMP * 64 * 4);
  float* Vps   = (float*)A((size_t)NSHIFT * 64 * 4);
  float* K2s   = (float*)A((size_t)NSHIFT * 64 * 4);
  float* W2e   = (float*)A((size_t)64 * 64 * 4);
  float* W2s   = (float*)A((size_t)64 * 64 * 4);
  unsigned short* fuseWb = (unsigned short*)A((size_t)192 * 64 * 2);
  int* row_all = (int*)A((size_t)(NT_CNT + 1) * 4);
  int* el_all  = (int*)A((size_t)ET_ALL * 4);
  uint2* staging = (uint2*)A((size_t)NBLK0 * SSTRIDE * 8);
  int* table   = (int*)A((size_t)(NBUCK + 1) * NBLK0 * 4);
  int* bstart  = (int*)A((size_t)(NBUCK + 1) * 4);

  // binned CSR over {sd, ve, vs}
  bin_kernel<<<NBLK0, 256, 0, stream>>>(sd_dst, sd_src, ve_var, ve_emp,
                                        vs_var, vs_shift, staging, table);
  bstart_kernel<<<1, 1024, 0, stream>>>(table, bstart);
  csr_build_kernel<<<NBUCK, 256, 0, stream>>>(staging, table, bstart, row_all, el_all);

  // Stage 0: all projections (h_con unused -> skipped)
  proj_all_kernel<<<750 + 7500 + 125000, 256, 0, stream>>>(
      x_emp, W_emp, b_emp, h_emp,
      x_shift, W_shift, b_shift, h_sh0,
      x_var, W_var, b_var, h_var);

  // Stage 1: GAT
  gat_x_kernel<<<(NSHIFT + 7) / 8, 256, 0, stream>>>(h_sh0, gat_W, att_s, att_d,
                                                     Xg, a_s, a_d, NSHIFT);
  gat_aggr_kernel<<<(NSHIFT + 3) / 4, 256, 0, stream>>>(Xg, a_s, a_d, row_all, el_all,
                                                        gat_b, h_sh0, h_sh1, NSHIFT);

  // Stage 2 prep
  small_prep_kernel<<<3, 256, 0, stream>>>(qW_e, kW_e, qW_s, kW_s, fuseW, W2e, W2s, fuseWb);
  linear_all_kernel<<<16500, 256, 0, stream>>>(h_emp, h_sh1,
      injW_e, injb_e, W2e, injW_s, injb_s, W2s, Vpe, K2e, Vps, K2s);

  // Stage 2+3 fused
  stage2_kernel<<<(NVAR + 63) / 64, 512, 0, stream>>>(h_var,
      K2e, Vpe, row_all + NSHIFT, el_all,
      K2s, Vps, row_all + NSHIFT + NVAR, el_all,
      fuseWb, fuseb, out, NVAR);
}

// Round 5
// 610.363 us; speedup vs baseline: 4.9274x; 1.1379x over previous
//
#include <hip/hip_runtime.h>
#include <math.h>

#define NEMP   3000
#define NSHIFT 30000
#define NVAR   500000
#define ESD    960000
#define EVE    500000
#define EVS    500000
#define NT_CNT (NSHIFT + NVAR + NVAR)      // combined segment count = 1,030,000
#define ET_ALL (ESD + EVE + EVS)           // combined edge count   = 1,960,000

// ---- binned CSR build geometry ----
#define NBUCK  959        // 469 sd buckets (64 keys) + 245 ve + 245 vs (2048 keys)
#define NBLK0  256        // bin pass blocks
#define CHUNK  7657       // ceil(ET_ALL / NBLK0)
#define SSTRIDE 7664      // staging stride per block (>= CHUNK, 8-aligned)

typedef __attribute__((ext_vector_type(8))) short short8;
typedef __attribute__((ext_vector_type(4))) float f32x4;

__device__ __forceinline__ unsigned short f2bf(float x) {
  unsigned u = __float_as_uint(x);
  unsigned r = (u + 0x7FFFu + ((u >> 16) & 1u)) >> 16;   // RNE
  return (unsigned short)r;
}

// ---------------- Stage 0: projections (emp + shift; var folded into stage2) --------
template<int F>
__device__ __forceinline__ void proj_body(const float* __restrict__ x,
    const float* __restrict__ W, const float* __restrict__ b,
    float* __restrict__ out, int blk, int N) {
  int n = __builtin_amdgcn_readfirstlane((int)(blk * 4 + (threadIdx.x >> 6)));
  int j = threadIdx.x & 63;
  if (n >= N) return;
  const float* xr = x + (size_t)n * F;
  float acc = b[j];
  #pragma unroll
  for (int f = 0; f < F; ++f) acc = fmaf(xr[f], W[f * 64 + j], acc);
  out[(size_t)n * 64 + j] = fmaxf(acc, 0.0f);
}

__global__ __launch_bounds__(256) void proj_all_kernel(
    const float* __restrict__ x_emp, const float* __restrict__ W_emp, const float* __restrict__ b_emp, float* __restrict__ h_emp,
    const float* __restrict__ x_shift, const float* __restrict__ W_shift, const float* __restrict__ b_shift, float* __restrict__ h_sh0,
    const float* __restrict__ w_as, const float* __restrict__ w_ad,
    float* __restrict__ a_s, float* __restrict__ a_d) {
  int blk = blockIdx.x;
  if (blk < 750) { proj_body<32>(x_emp, W_emp, b_emp, h_emp, blk, NEMP); return; }
  // shift projection + fused GAT attention coefficients
  int nb = blk - 750;
  int n = __builtin_amdgcn_readfirstlane((int)(nb * 4 + (threadIdx.x >> 6)));
  int j = threadIdx.x & 63;
  if (n >= NSHIFT) return;
  const float* xr = x_shift + (size_t)n * 24;
  float acc = b_shift[j];
  #pragma unroll
  for (int f = 0; f < 24; ++f) acc = fmaf(xr[f], W_shift[f * 64 + j], acc);
  float h = fmaxf(acc, 0.0f);
  h_sh0[(size_t)n * 64 + j] = h;
  const float4 was4 = *(const float4*)(w_as + j * 4);
  const float4 wad4 = *(const float4*)(w_ad + j * 4);
  float s0 = h * was4.x, s1 = h * was4.y, s2 = h * was4.z, s3 = h * was4.w;
  float d0 = h * wad4.x, d1 = h * wad4.y, d2 = h * wad4.z, d3 = h * wad4.w;
  #pragma unroll
  for (int o = 32; o > 0; o >>= 1) {
    s0 += __shfl_xor(s0, o); s1 += __shfl_xor(s1, o);
    s2 += __shfl_xor(s2, o); s3 += __shfl_xor(s3, o);
    d0 += __shfl_xor(d0, o); d1 += __shfl_xor(d1, o);
    d2 += __shfl_xor(d2, o); d3 += __shfl_xor(d3, o);
  }
  if (j == 0) {
    *(float4*)(a_s + n * 4) = make_float4(s0, s1, s2, s3);
    *(float4*)(a_d + n * 4) = make_float4(d0, d1, d2, d3);
  }
}

// ---------------- prep: qkfold x2, fuseW bf16 swizzle, att fold, GAT-W bf16 swizzle ----
__device__ __forceinline__ void qkfold_body(const float* __restrict__ qW,
    const float* __restrict__ kW, float* __restrict__ W2) {
  int j = threadIdx.x & 63;
  int fq = threadIdx.x >> 6;
  for (int ff = 0; ff < 16; ++ff) {
    int f = fq * 16 + ff;
    float acc = 0.0f;
    #pragma unroll
    for (int d = 0; d < 64; ++d) acc = fmaf(qW[j * 64 + d], kW[f * 64 + d], acc);
    W2[f * 64 + j] = 0.125f * acc;
  }
}

__global__ __launch_bounds__(256) void small_prep_kernel(
    const float* __restrict__ qWe, const float* __restrict__ kWe,
    const float* __restrict__ qWs, const float* __restrict__ kWs,
    const float* __restrict__ fuseW, const float* __restrict__ gat_W,
    const float* __restrict__ att_src, const float* __restrict__ att_dst,
    float* __restrict__ W2e, float* __restrict__ W2s,
    unsigned short* __restrict__ fuseWb,
    float* __restrict__ w_as, float* __restrict__ w_ad,
    unsigned short* __restrict__ Wrb) {
  int t = threadIdx.x;
  if (blockIdx.x == 0) { qkfold_body(qWe, kWe, W2e); return; }
  if (blockIdx.x == 1) { qkfold_body(qWs, kWs, W2s); return; }
  if (blockIdx.x == 2) {
    // fuse frag order: idx=((nt*6+kb)*64+lane)*8+i ; k=kb*32+(lane>>4)*8+i ; n=nt*16+(lane&15)
    for (int linear = t; linear < 192 * 64; linear += 256) {
      int i    = linear & 7;
      int lane = (linear >> 3) & 63;
      int g    = linear >> 9;          // nt*6 + kb
      int kb   = g % 6, nt = g / 6;
      int k = kb * 32 + (lane >> 4) * 8 + i;
      int n = nt * 16 + (lane & 15);
      fuseWb[linear] = f2bf(fuseW[k * 64 + n]);
    }
    return;
  }
  if (blockIdx.x == 3) {
    // w_as[f*4+h] = sum_d gat_W[f*256 + h*64 + d] * att_src[h*64+d]
    int h = t >> 6, f = t & 63;
    float as = 0.0f, ad = 0.0f;
    #pragma unroll
    for (int d = 0; d < 64; ++d) {
      float wv = gat_W[f * 256 + h * 64 + d];
      as = fmaf(wv, att_src[h * 64 + d], as);
      ad = fmaf(wv, att_dst[h * 64 + d], ad);
    }
    w_as[f * 4 + h] = as;
    w_ad[f * 4 + h] = ad;
    return;
  }
  // block 4: GAT phase-2 weights: Wr[k=h*64+f][j] = 0.25*gat_W[f*256+h*64+j], bf16 frags
  // idx = ((nt*8+kb)*64+lane)*8+i ; k = kb*32+(lane>>4)*8+i ; j = nt*16+(lane&15)
  for (int linear = t; linear < 4 * 8 * 64 * 8; linear += 256) {
    int i    = linear & 7;
    int lane = (linear >> 3) & 63;
    int g    = linear >> 9;          // nt*8 + kb
    int kb   = g & 7, nt = g >> 3;
    int k = kb * 32 + ((lane >> 4) << 3) + i;
    int j = nt * 16 + (lane & 15);
    Wrb[linear] = f2bf(0.25f * gat_W[(k & 63) * 256 + (k >> 6) * 64 + j]);
  }
}

// ---------------- merged linear64: 4 jobs ----------------
__global__ __launch_bounds__(256) void linear_all_kernel(
    const float* __restrict__ h_emp, const float* __restrict__ h_sh1,
    const float* __restrict__ injW_e, const float* __restrict__ injb_e, const float* __restrict__ W2e,
    const float* __restrict__ injW_s, const float* __restrict__ injb_s, const float* __restrict__ W2s,
    float* __restrict__ Vpe, float* __restrict__ K2e,
    float* __restrict__ Vps, float* __restrict__ K2s) {
  int b = blockIdx.x;
  const float *h, *W, *bias; float* out; int nb, N;
  if (b < 750)        { h = h_emp; W = injW_e; bias = injb_e; out = Vpe; nb = b;        N = NEMP; }
  else if (b < 1500)  { h = h_emp; W = W2e;    bias = nullptr; out = K2e; nb = b - 750; N = NEMP; }
  else if (b < 9000)  { h = h_sh1; W = injW_s; bias = injb_s; out = Vps; nb = b - 1500; N = NSHIFT; }
  else                { h = h_sh1; W = W2s;    bias = nullptr; out = K2s; nb = b - 9000; N = NSHIFT; }
  int n = __builtin_amdgcn_readfirstlane((int)(nb * 4 + (threadIdx.x >> 6)));
  int j = threadIdx.x & 63;
  if (n >= N) return;
  const float* hr = h + (size_t)n * 64;
  float acc = bias ? bias[j] : 0.0f;
  #pragma unroll
  for (int f = 0; f < 64; ++f) acc = fmaf(hr[f], W[f * 64 + j], acc);
  out[(size_t)n * 64 + j] = acc;
}

// ---------------- binned CSR build ----------------
__device__ __forceinline__ void edge_decode(int i,
    const int* __restrict__ sd_dst, const int* __restrict__ sd_src,
    const int* __restrict__ ve_var, const int* __restrict__ ve_emp,
    const int* __restrict__ vs_var, const int* __restrict__ vs_shift,
    int& b, int& lk, int& val) {
  if (i < ESD)            { int d = sd_dst[i]; b = d >> 6; lk = d & 63; val = sd_src[i]; }
  else if (i < ESD + EVE) { int j = i - ESD; int d = ve_var[j]; b = 469 + (d >> 11); lk = d & 2047; val = ve_emp[j]; }
  else                    { int j = i - ESD - EVE; int d = vs_var[j]; b = 714 + (d >> 11); lk = d & 2047; val = vs_shift[j]; }
}

__global__ __launch_bounds__(256) void bin_kernel(
    const int* __restrict__ sd_dst, const int* __restrict__ sd_src,
    const int* __restrict__ ve_var, const int* __restrict__ ve_emp,
    const int* __restrict__ vs_var, const int* __restrict__ vs_shift,
    uint2* __restrict__ staging, int* __restrict__ table) {
  __shared__ int hist[NBUCK];
  __shared__ int sums[256];
  int t = threadIdx.x, blk = blockIdx.x;
  int e0 = blk * CHUNK;
  int e1 = min(e0 + CHUNK, ET_ALL);
  int sbase = blk * SSTRIDE;
  for (int i = t; i < NBUCK; i += 256) hist[i] = 0;
  __syncthreads();
  for (int i = e0 + t; i < e1; i += 256) {
    int b, lk, val;
    edge_decode(i, sd_dst, sd_src, ve_var, ve_emp, vs_var, vs_shift, b, lk, val);
    atomicAdd(&hist[b], 1);
  }
  __syncthreads();
  int base = t * 4, v[4], s = 0;
  #pragma unroll
  for (int k = 0; k < 4; ++k) { int i = base + k; v[k] = (i < NBUCK) ? hist[i] : 0; s += v[k]; }
  sums[t] = s; __syncthreads();
  for (int o = 1; o < 256; o <<= 1) {
    int add = (t >= o) ? sums[t - o] : 0;
    __syncthreads(); sums[t] += add; __syncthreads();
  }
  int run = sums[t] - s;
  #pragma unroll
  for (int k = 0; k < 4; ++k) {
    int i = base + k;
    if (i < NBUCK) { hist[i] = run; table[i * NBLK0 + blk] = sbase + run; run += v[k]; }
  }
  if (t == 0) table[NBUCK * NBLK0 + blk] = sbase + (e1 - e0);
  __syncthreads();
  for (int i = e0 + t; i < e1; i += 256) {
    int b, lk, val;
    edge_decode(i, sd_dst, sd_src, ve_var, ve_emp, vs_var, vs_shift, b, lk, val);
    int pos = sbase + atomicAdd(&hist[b], 1);
    staging[pos] = make_uint2((unsigned)lk, (unsigned)val);
  }
}

__global__ __launch_bounds__(1024) void bstart_kernel(const int* __restrict__ table,
                                                      int* __restrict__ bstart) {
  __shared__ int histL[NBUCK];
  __shared__ int sd[1024];
  int t = threadIdx.x;
  for (int i = t; i < NBUCK; i += 1024) histL[i] = 0;
  __syncthreads();
  for (int idx = t; idx < NBUCK * NBLK0; idx += 1024) {
    int len = table[idx + NBLK0] - table[idx];
    if (len) atomicAdd(&histL[idx >> 8], len);
  }
  __syncthreads();
  int v = (t < NBUCK) ? histL[t] : 0;
  sd[t] = v; __syncthreads();
  for (int o = 1; o < 1024; o <<= 1) {
    int add = (t >= o) ? sd[t - o] : 0;
    __syncthreads(); sd[t] += add; __syncthreads();
  }
  if (t < NBUCK) bstart[t] = sd[t] - v;
  if (t == NBUCK - 1) bstart[NBUCK] = sd[t];
}

__global__ __launch_bounds__(256) void csr_build_kernel(
    const uint2* __restrict__ staging, const int* __restrict__ table,
    const int* __restrict__ bstart, int* __restrict__ row, int* __restrict__ elist) {
  __shared__ int segstart[NBLK0];
  __shared__ int cum[NBLK0];
  __shared__ int hist[2048];
  __shared__ int sums[256];
  int b = blockIdx.x, t = threadIdx.x;
  {
    int s0 = table[b * NBLK0 + t];
    int s1 = table[(b + 1) * NBLK0 + t];
    segstart[t] = s0;
    cum[t] = s1 - s0;
  }
  for (int i = t; i < 2048; i += 256) hist[i] = 0;
  __syncthreads();
  for (int o = 1; o < NBLK0; o <<= 1) {
    int add = (t >= o) ? cum[t - o] : 0;
    __syncthreads(); cum[t] += add; __syncthreads();
  }
  int total = cum[NBLK0 - 1];
  int keyBase, kcount;
  if (b < 469)      { keyBase = b * 64;                     kcount = min(64,   30000  - b * 64); }
  else if (b < 714) { int lb = b - 469; keyBase = 30000  + lb * 2048; kcount = min(2048, 500000 - lb * 2048); }
  else              { int lb = b - 714; keyBase = 530000 + lb * 2048; kcount = min(2048, 500000 - lb * 2048); }
  for (int idx = t; idx < total; idx += 256) {
    int lo = 0, hi = NBLK0 - 1;
    while (lo < hi) { int mid = (lo + hi) >> 1; if (cum[mid] > idx) hi = mid; else lo = mid + 1; }
    int off = idx - (lo ? cum[lo - 1] : 0);
    unsigned lk = staging[segstart[lo] + off].x;
    atomicAdd(&hist[lk], 1);
  }
  __syncthreads();
  int bs = bstart[b];
  int base = t * 8, v[8], s = 0;
  #pragma unroll
  for (int k = 0; k < 8; ++k) { int i = base + k; v[k] = (i < kcount) ? hist[i] : 0; s += v[k]; }
  sums[t] = s; __syncthreads();
  for (int o = 1; o < 256; o <<= 1) {
    int add = (t >= o) ? sums[t - o] : 0;
    __syncthreads(); sums[t] += add; __syncthreads();
  }
  int run = sums[t] - s;
  #pragma unroll
  for (int k = 0; k < 8; ++k) {
    int i = base + k;
    if (i < kcount) { hist[i] = run; row[keyBase + i] = bs + run; run += v[k]; }
  }
  if (b == NBUCK - 1 && t == 0) row[NT_CNT] = bstart[NBUCK];
  __syncthreads();
  for (int idx = t; idx < total; idx += 256) {
    int lo = 0, hi = NBLK0 - 1;
    while (lo < hi) { int mid = (lo + hi) >> 1; if (cum[mid] > idx) hi = mid; else lo = mid + 1; }
    int off = idx - (lo ? cum[lo - 1] : 0);
    uint2 p = staging[segstart[lo] + off];
    int pos = bs + atomicAdd(&hist[p.x], 1);
    elist[pos] = (int)p.y;
  }
}

// ---------------- Stage 1: GAT aggregate (gather h_sh0, MFMA apply W) ----------------
__global__ __launch_bounds__(512) void gat_aggr_kernel(
    const float* __restrict__ h_sh0,
    const float* __restrict__ a_s, const float* __restrict__ a_d,
    const int* __restrict__ row, const int* __restrict__ elist,
    const unsigned short* __restrict__ Wrb, const float* __restrict__ gat_b,
    float* __restrict__ h_sh1, int N) {
  __shared__ float aggT[256][65];   // [k = h*64+f][node-col]
  int tid = threadIdx.x, lane = tid & 63;
  int w = __builtin_amdgcn_readfirstlane((int)(tid >> 6));
  int blockStart = blockIdx.x * 64;

  // phase 1: per-node alpha-weighted h_sh0 accumulation (wave per node, lane = feature)
  for (int k = 0; k < 8; ++k) {
    int c = w * 8 + k;
    int n = blockStart + c;
    float4 ad4 = make_float4(0.f, 0.f, 0.f, 0.f);
    int b = 0, e = 0;
    if (n < N) { b = row[n]; e = row[n + 1]; ad4 = *(const float4*)(a_d + n * 4); }
    float g0 = 0, g1 = 0, g2 = 0, g3 = 0, z0 = 0, z1 = 0, z2 = 0, z3 = 0;
    for (int p = b; p < e; ++p) {
      int s = elist[p];
      const float4 as4 = *(const float4*)(a_s + s * 4);
      float e0 = as4.x + ad4.x, e1 = as4.y + ad4.y;
      float e2 = as4.z + ad4.z, e3 = as4.w + ad4.w;
      e0 = e0 > 0.f ? e0 : 0.2f * e0;  e1 = e1 > 0.f ? e1 : 0.2f * e1;
      e2 = e2 > 0.f ? e2 : 0.2f * e2;  e3 = e3 > 0.f ? e3 : 0.2f * e3;
      float x0 = __expf(e0), x1 = __expf(e1), x2 = __expf(e2), x3 = __expf(e3);
      float hv = h_sh0[(size_t)s * 64 + lane];
      z0 += x0; z1 += x1; z2 += x2; z3 += x3;
      g0 = fmaf(x0, hv, g0); g1 = fmaf(x1, hv, g1);
      g2 = fmaf(x2, hv, g2); g3 = fmaf(x3, hv, g3);
    }
    aggT[lane][c]       = g0 / fmaxf(z0, 1e-16f);
    aggT[64 + lane][c]  = g1 / fmaxf(z1, 1e-16f);
    aggT[128 + lane][c] = g2 / fmaxf(z2, 1e-16f);
    aggT[192 + lane][c] = g3 / fmaxf(z3, 1e-16f);
  }
  __syncthreads();

  // phase 2: h_sh1 = relu(agg @ Wr + b) + h_sh0   via bf16 MFMA (0.25 folded in Wr)
  {
    int mtile = w >> 1;
    int row16 = lane & 15, blk = lane >> 4;
    int mrow = mtile * 16 + row16;
    #pragma unroll
    for (int t = 0; t < 2; ++t) {
      int ntile = (w & 1) * 2 + t;
      f32x4 acc = {0.f, 0.f, 0.f, 0.f};
      #pragma unroll
      for (int kb = 0; kb < 8; ++kb) {
        short8 a;
        #pragma unroll
        for (int i = 0; i < 8; ++i)
          a[i] = (short)f2bf(aggT[kb * 32 + blk * 8 + i][mrow]);
        short8 bfr = *(const short8*)(Wrb + (((ntile * 8 + kb) * 64 + lane) << 3));
        acc = __builtin_amdgcn_mfma_f32_16x16x32_bf16(a, bfr, acc, 0, 0, 0);
      }
      int j = ntile * 16 + row16;
      float gb = gat_b[j];
      #pragma unroll
      for (int r = 0; r < 4; ++r) {
        int node = blockStart + mtile * 16 + blk * 4 + r;
        if (node < N) {
          float o = fmaxf(acc[r] + gb, 0.0f) + h_sh0[(size_t)node * 64 + j];
          h_sh1[(size_t)node * 64 + j] = o;
        }
      }
    }
  }
}

// ---------------- Stage 2+3 fused: var-proj + inject x2 + MFMA fuse + L2 norm ----------
__global__ __launch_bounds__(512) void stage2_kernel(
    const float* __restrict__ x_var, const float* __restrict__ W_var,
    const float* __restrict__ b_var,
    const float* __restrict__ K2e, const float* __restrict__ Vpe,
    const int* __restrict__ ve_row, const int* __restrict__ ve_src,
    const float* __restrict__ K2s, const float* __restrict__ Vps,
    const int* __restrict__ vs_row, const int* __restrict__ vs_src,
    const unsigned short* __restrict__ fuseWb, const float* __restrict__ fuseb,
    float* __restrict__ out, int N) {
  __shared__ float fT[192][65];   // [feature][node-col]
  __shared__ float ssq2[64][2];
  int tid = threadIdx.x;
  int lane = tid & 63;
  int w = __builtin_amdgcn_readfirstlane((int)(tid >> 6));   // 0..7
  int g = lane >> 4, sl = lane & 15;
  int blockStart = blockIdx.x * 64;

  // ---- Phase A: compute h_var in-kernel + injections; wave w owns cols w*8..w*8+7 ----
  for (int k = 0; k < 2; ++k) {
    int c = w * 8 + k * 4 + g;
    int n = blockStart + c;
    bool act = (n < N);
    float4 hv = make_float4(0.f, 0.f, 0.f, 0.f);
    if (act) {
      const float* xr = x_var + (size_t)n * 19;
      const float* Wv = W_var + sl * 4;
      float4 a4 = *(const float4*)(b_var + sl * 4);
      #pragma unroll
      for (int f = 0; f < 19; ++f) {
        float xf = xr[f];
        const float4 w4 = *(const float4*)(Wv + f * 64);
        a4.x = fmaf(xf, w4.x, a4.x); a4.y = fmaf(xf, w4.y, a4.y);
        a4.z = fmaf(xf, w4.z, a4.z); a4.w = fmaf(xf, w4.w, a4.w);
      }
      hv.x = fmaxf(a4.x, 0.f); hv.y = fmaxf(a4.y, 0.f);
      hv.z = fmaxf(a4.z, 0.f); hv.w = fmaxf(a4.w, 0.f);
    }
    fT[sl * 4 + 0][c] = hv.x; fT[sl * 4 + 1][c] = hv.y;
    fT[sl * 4 + 2][c] = hv.z; fT[sl * 4 + 3][c] = hv.w;

    #pragma unroll
    for (int which = 0; which < 2; ++which) {
      const int*   rowp = which ? vs_row : ve_row;
      const int*   srcp = which ? vs_src : ve_src;
      const float* K2   = which ? K2s : K2e;
      const float* Vp   = which ? Vps : Vpe;
      int outBase = which ? 128 : 64;
      int b = 0, e = 0;
      if (act) { b = rowp[n]; e = rowp[n + 1]; }
      float4 msg = make_float4(0.f, 0.f, 0.f, 0.f);
      if (e - b == 1) {
        // softmax of a single edge == 1 -> msg = V[src], no score needed
        int s = srcp[b];
        msg = *(const float4*)(Vp + (size_t)s * 64 + sl * 4);
      } else if (e > b) {
        float4 acc = make_float4(0.f, 0.f, 0.f, 0.f);
        float z = 0.0f;
        for (int p = b; p < e; ++p) {
          int s = srcp[p];
          const float4 k4 = *(const float4*)(K2 + (size_t)s * 64 + sl * 4);
          float part = hv.x * k4.x + hv.y * k4.y + hv.z * k4.z + hv.w * k4.w;
          part += __shfl_xor(part, 1); part += __shfl_xor(part, 2);
          part += __shfl_xor(part, 4); part += __shfl_xor(part, 8);
          float ex = __expf(part);
          z += ex;
          const float4 v4 = *(const float4*)(Vp + (size_t)s * 64 + sl * 4);
          acc.x = fmaf(ex, v4.x, acc.x); acc.y = fmaf(ex, v4.y, acc.y);
          acc.z = fmaf(ex, v4.z, acc.z); acc.w = fmaf(ex, v4.w, acc.w);
        }
        float inv = 1.0f / fmaxf(z, 1e-9f);
        msg.x = acc.x * inv; msg.y = acc.y * inv;
        msg.z = acc.z * inv; msg.w = acc.w * inv;
      }
      fT[outBase + sl * 4 + 0][c] = msg.x;
      fT[outBase + sl * 4 + 1][c] = msg.y;
      fT[outBase + sl * 4 + 2][c] = msg.z;
      fT[outBase + sl * 4 + 3][c] = msg.w;
    }
  }
  __syncthreads();

  // ---- Phase B: fuse matmul via bf16 MFMA 16x16x32 ----
  {
    int mtile = w >> 1;
    int row16 = lane & 15, blk = lane >> 4;
    int mrow = mtile * 16 + row16;
    float nodeSS[4] = {0.f, 0.f, 0.f, 0.f};
    #pragma unroll
    for (int t = 0; t < 2; ++t) {
      int ntile = (w & 1) * 2 + t;
      f32x4 acc = {0.f, 0.f, 0.f, 0.f};
      #pragma unroll
      for (int kb = 0; kb < 6; ++kb) {
        short8 a;
        #pragma unroll
        for (int i = 0; i < 8; ++i)
          a[i] = (short)f2bf(fT[kb * 32 + blk * 8 + i][mrow]);
        short8 bfr = *(const short8*)(fuseWb + (((ntile * 6 + kb) * 64 + lane) << 3));
        acc = __builtin_amdgcn_mfma_f32_16x16x32_bf16(a, bfr, acc, 0, 0, 0);
      }
      float fb = fuseb[ntile * 16 + row16];
      #pragma unroll
      for (int r = 0; r < 4; ++r) {
        float v = fmaxf(acc[r] + fb, 0.0f);
        float vv = v * v;
        vv += __shfl_xor(vv, 1); vv += __shfl_xor(vv, 2);
        vv += __shfl_xor(vv, 4); vv += __shfl_xor(vv, 8);
        nodeSS[r] += vv;
      }
    }
    if (row16 == 0) {
      #pragma unroll
      for (int r = 0; r < 4; ++r)
        ssq2[mtile * 16 + blk * 4 + r][w & 1] = nodeSS[r];
    }
  }
  __syncthreads();
  if (tid < 64) {
    int n = blockStart + tid;
    if (n < N) out[n] = sqrtf(ssq2[tid][0] + ssq2[tid][1]);
  }
}

// ---------------- host ----------------
extern "C" void kernel_launch(void* const* d_in, const int* in_sizes, int n_in,
                              void* d_out, int out_size, void* d_ws, size_t ws_size,
                              hipStream_t stream) {
  const float* x_emp   = (const float*)d_in[0];
  const float* x_shift = (const float*)d_in[1];
  const float* x_var   = (const float*)d_in[2];
  const float* W_emp   = (const float*)d_in[4];
  const float* b_emp   = (const float*)d_in[5];
  const float* W_shift = (const float*)d_in[6];
  const float* b_shift = (const float*)d_in[7];
  const float* W_var   = (const float*)d_in[8];
  const float* b_var   = (const float*)d_in[9];
  const float* gat_W   = (const float*)d_in[12];
  const float* att_s   = (const float*)d_in[13];
  const float* att_d   = (const float*)d_in[14];
  const float* gat_b   = (const float*)d_in[15];
  const float* injW_e  = (const float*)d_in[16];
  const float* injb_e  = (const float*)d_in[17];
  const float* injW_s  = (const float*)d_in[18];
  const float* injb_s  = (const float*)d_in[19];
  const float* qW_e    = (const float*)d_in[20];
  const float* kW_e    = (const float*)d_in[21];
  const float* qW_s    = (const float*)d_in[22];
  const float* kW_s    = (const float*)d_in[23];
  const float* fuseW   = (const float*)d_in[24];
  const float* fuseb   = (const float*)d_in[25];
  const int* sd_src  = (const int*)d_in[26];
  const int* sd_dst  = (const int*)d_in[27];
  const int* ve_var  = (const int*)d_in[28];
  const int* ve_emp  = (const int*)d_in[29];
  const int* vs_var  = (const int*)d_in[30];
  const int* vs_shift= (const int*)d_in[31];
  float* out = (float*)d_out;

  char* base = (char*)d_ws;
  size_t off = 0;
  auto A = [&](size_t nbytes) -> void* {
    void* r = base + off;
    off = (off + nbytes + 255) & ~(size_t)255;
    return r;
  };
  float* h_emp = (float*)A((size_t)NEMP * 64 * 4);
  float* h_sh0 = (float*)A((size_t)NSHIFT * 64 * 4);
  float* h_sh1 = (float*)A((size_t)NSHIFT * 64 * 4);
  float* a_s   = (float*)A((size_t)NSHIFT * 4 * 4);
  float* a_d   = (float*)A((size_t)NSHIFT * 4 * 4);
  float* Vpe   = (float*)A((size_t)NEMP * 64 * 4);
  float* K2e   = (float*)A((size_t)NEMP * 64 * 4);
  float* Vps   = (float*)A((size_t)NSHIFT * 64 * 4);
  float* K2s   = (float*)A((size_t)NSHIFT * 64 * 4);
  float* W2e   = (float*)A((size_t)64 * 64 * 4);
  float* W2s   = (float*)A((size_t)64 * 64 * 4);
  float* w_as  = (float*)A((size_t)64 * 4 * 4);
  float* w_ad  = (float*)A((size_t)64 * 4 * 4);
  unsigned short* fuseWb = (unsigned short*)A((size_t)192 * 64 * 2);
  unsigned short* Wrb    = (unsigned short*)A((size_t)256 * 64 * 2);
  int* row_all = (int*)A((size_t)(NT_CNT + 1) * 4);
  int* el_all  = (int*)A((size_t)ET_ALL * 4);
  uint2* staging = (uint2*)A((size_t)NBLK0 * SSTRIDE * 8);
  int* table   = (int*)A((size_t)(NBUCK + 1) * NBLK0 * 4);
  int* bstart  = (int*)A((size_t)(NBUCK + 1) * 4);

  // prep (weight folds) first: proj_all depends on w_as/w_ad
  small_prep_kernel<<<5, 256, 0, stream>>>(qW_e, kW_e, qW_s, kW_s, fuseW, gat_W,
                                           att_s, att_d, W2e, W2s, fuseWb,
                                           w_as, w_ad, Wrb);

  // binned CSR over {sd, ve, vs}
  bin_kernel<<<NBLK0, 256, 0, stream>>>(sd_dst, sd_src, ve_var, ve_emp,
                                        vs_var, vs_shift, staging, table);
  bstart_kernel<<<1, 1024, 0, stream>>>(table, bstart);
  csr_build_kernel<<<NBUCK, 256, 0, stream>>>(staging, table, bstart, row_all, el_all);

  // Stage 0: emp + shift projections (+ fused a_s/a_d); var proj folded into stage2
  proj_all_kernel<<<750 + 7500, 256, 0, stream>>>(
      x_emp, W_emp, b_emp, h_emp,
      x_shift, W_shift, b_shift, h_sh0,
      w_as, w_ad, a_s, a_d);

  // Stage 1: GAT (gather h_sh0 + MFMA weight apply)
  gat_aggr_kernel<<<(NSHIFT + 63) / 64, 512, 0, stream>>>(
      h_sh0, a_s, a_d, row_all, el_all, Wrb, gat_b, h_sh1, NSHIFT);

  // Stage 2 prep
  linear_all_kernel<<<16500, 256, 0, stream>>>(h_emp, h_sh1,
      injW_e, injb_e, W2e, injW_s, injb_s, W2s, Vpe, K2e, Vps, K2s);

  // Stage 2+3 fused
  stage2_kernel<<<(NVAR + 63) / 64, 512, 0, stream>>>(x_var, W_var, b_var,
      K2e, Vpe, row_all + NSHIFT, el_all,
      K2s, Vps, row_all + NSHIFT + NVAR, el_all,
      fuseWb, fuseb, out, NVAR);
}

// Round 6
// 568.999 us; speedup vs baseline: 5.2856x; 1.0727x over previous
//
#include <hip/hip_runtime.h>
#include <math.h>

#define NEMP   3000
#define NSHIFT 30000
#define NVAR   500000
#define ESD    960000
#define EVE    500000
#define EVS    500000
#define NT_CNT (NSHIFT + NVAR + NVAR)      // combined segment count = 1,030,000
#define ET_ALL (ESD + EVE + EVS)           // combined edge count   = 1,960,000

// ---- binned CSR build geometry ----
#define NBUCK  959        // 469 sd buckets (64 keys) + 245 ve + 245 vs (2048 keys)
#define NBLK0  256        // bin pass blocks
#define CHUNK  7657       // ceil(ET_ALL / NBLK0)
#define SSTRIDE 7664      // staging stride per block (>= CHUNK, 8-aligned)

typedef __attribute__((ext_vector_type(8))) short short8;
typedef __attribute__((ext_vector_type(4))) float f32x4;

__device__ __forceinline__ unsigned short f2bf(float x) {
  unsigned u = __float_as_uint(x);
  unsigned r = (u + 0x7FFFu + ((u >> 16) & 1u)) >> 16;   // RNE
  return (unsigned short)r;
}
__device__ __forceinline__ float bf2f(unsigned short u) {
  return __uint_as_float((unsigned)u << 16);
}

// ---------------- Stage 0: projections (emp + shift; var folded into stage2) --------
template<int F>
__device__ __forceinline__ void proj_body(const float* __restrict__ x,
    const float* __restrict__ W, const float* __restrict__ b,
    float* __restrict__ out, int blk, int N) {
  int n = __builtin_amdgcn_readfirstlane((int)(blk * 4 + (threadIdx.x >> 6)));
  int j = threadIdx.x & 63;
  if (n >= N) return;
  const float* xr = x + (size_t)n * F;
  float acc = b[j];
  #pragma unroll
  for (int f = 0; f < F; ++f) acc = fmaf(xr[f], W[f * 64 + j], acc);
  out[(size_t)n * 64 + j] = fmaxf(acc, 0.0f);
}

__global__ __launch_bounds__(256) void proj_all_kernel(
    const float* __restrict__ x_emp, const float* __restrict__ W_emp, const float* __restrict__ b_emp, float* __restrict__ h_emp,
    const float* __restrict__ x_shift, const float* __restrict__ W_shift, const float* __restrict__ b_shift, float* __restrict__ h_sh0,
    unsigned short* __restrict__ h_sh0b,
    const float* __restrict__ w_as, const float* __restrict__ w_ad,
    float* __restrict__ a_s, float* __restrict__ a_d) {
  int blk = blockIdx.x;
  if (blk < 750) { proj_body<32>(x_emp, W_emp, b_emp, h_emp, blk, NEMP); return; }
  // shift projection + fused GAT attention coefficients + bf16 copy
  int nb = blk - 750;
  int n = __builtin_amdgcn_readfirstlane((int)(nb * 4 + (threadIdx.x >> 6)));
  int j = threadIdx.x & 63;
  if (n >= NSHIFT) return;
  const float* xr = x_shift + (size_t)n * 24;
  float acc = b_shift[j];
  #pragma unroll
  for (int f = 0; f < 24; ++f) acc = fmaf(xr[f], W_shift[f * 64 + j], acc);
  float h = fmaxf(acc, 0.0f);
  h_sh0[(size_t)n * 64 + j] = h;
  h_sh0b[(size_t)n * 64 + j] = f2bf(h);
  const float4 was4 = *(const float4*)(w_as + j * 4);
  const float4 wad4 = *(const float4*)(w_ad + j * 4);
  float s0 = h * was4.x, s1 = h * was4.y, s2 = h * was4.z, s3 = h * was4.w;
  float d0 = h * wad4.x, d1 = h * wad4.y, d2 = h * wad4.z, d3 = h * wad4.w;
  #pragma unroll
  for (int o = 32; o > 0; o >>= 1) {
    s0 += __shfl_xor(s0, o); s1 += __shfl_xor(s1, o);
    s2 += __shfl_xor(s2, o); s3 += __shfl_xor(s3, o);
    d0 += __shfl_xor(d0, o); d1 += __shfl_xor(d1, o);
    d2 += __shfl_xor(d2, o); d3 += __shfl_xor(d3, o);
  }
  if (j == 0) {
    *(float4*)(a_s + n * 4) = make_float4(s0, s1, s2, s3);
    *(float4*)(a_d + n * 4) = make_float4(d0, d1, d2, d3);
  }
}

// ---------------- prep: qkfold x2, fuseW bf16 swizzle, att fold, GAT-W bf16 swizzle ----
__device__ __forceinline__ void qkfold_body(const float* __restrict__ qW,
    const float* __restrict__ kW, float* __restrict__ W2) {
  int j = threadIdx.x & 63;
  int fq = threadIdx.x >> 6;
  for (int ff = 0; ff < 16; ++ff) {
    int f = fq * 16 + ff;
    float acc = 0.0f;
    #pragma unroll
    for (int d = 0; d < 64; ++d) acc = fmaf(qW[j * 64 + d], kW[f * 64 + d], acc);
    W2[f * 64 + j] = 0.125f * acc;
  }
}

__global__ __launch_bounds__(256) void small_prep_kernel(
    const float* __restrict__ qWe, const float* __restrict__ kWe,
    const float* __restrict__ qWs, const float* __restrict__ kWs,
    const float* __restrict__ fuseW, const float* __restrict__ gat_W,
    const float* __restrict__ att_src, const float* __restrict__ att_dst,
    float* __restrict__ W2e, float* __restrict__ W2s,
    unsigned short* __restrict__ fuseWb,
    float* __restrict__ w_as, float* __restrict__ w_ad,
    unsigned short* __restrict__ Wrb) {
  int t = threadIdx.x;
  if (blockIdx.x == 0) { qkfold_body(qWe, kWe, W2e); return; }
  if (blockIdx.x == 1) { qkfold_body(qWs, kWs, W2s); return; }
  if (blockIdx.x == 2) {
    // fuse frag order: idx=((nt*6+kb)*64+lane)*8+i ; k=kb*32+(lane>>4)*8+i ; n=nt*16+(lane&15)
    for (int linear = t; linear < 192 * 64; linear += 256) {
      int i    = linear & 7;
      int lane = (linear >> 3) & 63;
      int g    = linear >> 9;          // nt*6 + kb
      int kb   = g % 6, nt = g / 6;
      int k = kb * 32 + (lane >> 4) * 8 + i;
      int n = nt * 16 + (lane & 15);
      fuseWb[linear] = f2bf(fuseW[k * 64 + n]);
    }
    return;
  }
  if (blockIdx.x == 3) {
    // w_as[f*4+h] = sum_d gat_W[f*256 + h*64 + d] * att_src[h*64+d]
    int h = t >> 6, f = t & 63;
    float as = 0.0f, ad = 0.0f;
    #pragma unroll
    for (int d = 0; d < 64; ++d) {
      float wv = gat_W[f * 256 + h * 64 + d];
      as = fmaf(wv, att_src[h * 64 + d], as);
      ad = fmaf(wv, att_dst[h * 64 + d], ad);
    }
    w_as[f * 4 + h] = as;
    w_ad[f * 4 + h] = ad;
    return;
  }
  // block 4: GAT phase-2 weights: Wr[k=h*64+f][j] = 0.25*gat_W[f*256+h*64+j], bf16 frags
  for (int linear = t; linear < 4 * 8 * 64 * 8; linear += 256) {
    int i    = linear & 7;
    int lane = (linear >> 3) & 63;
    int g    = linear >> 9;          // nt*8 + kb
    int kb   = g & 7, nt = g >> 3;
    int k = kb * 32 + ((lane >> 4) << 3) + i;
    int j = nt * 16 + (lane & 15);
    Wrb[linear] = f2bf(0.25f * gat_W[(k & 63) * 256 + (k >> 6) * 64 + j]);
  }
}

// ---------------- merged linear64: 4 jobs, bf16 outputs ----------------
__global__ __launch_bounds__(256) void linear_all_kernel(
    const float* __restrict__ h_emp, const float* __restrict__ h_sh1,
    const float* __restrict__ injW_e, const float* __restrict__ injb_e, const float* __restrict__ W2e,
    const float* __restrict__ injW_s, const float* __restrict__ injb_s, const float* __restrict__ W2s,
    unsigned short* __restrict__ Vpe, unsigned short* __restrict__ K2e,
    unsigned short* __restrict__ Vps, unsigned short* __restrict__ K2s) {
  int b = blockIdx.x;
  const float *h, *W, *bias; unsigned short* out; int nb, N;
  if (b < 750)        { h = h_emp; W = injW_e; bias = injb_e; out = Vpe; nb = b;        N = NEMP; }
  else if (b < 1500)  { h = h_emp; W = W2e;    bias = nullptr; out = K2e; nb = b - 750; N = NEMP; }
  else if (b < 9000)  { h = h_sh1; W = injW_s; bias = injb_s; out = Vps; nb = b - 1500; N = NSHIFT; }
  else                { h = h_sh1; W = W2s;    bias = nullptr; out = K2s; nb = b - 9000; N = NSHIFT; }
  int n = __builtin_amdgcn_readfirstlane((int)(nb * 4 + (threadIdx.x >> 6)));
  int j = threadIdx.x & 63;
  if (n >= N) return;
  const float* hr = h + (size_t)n * 64;
  float acc = bias ? bias[j] : 0.0f;
  #pragma unroll
  for (int f = 0; f < 64; ++f) acc = fmaf(hr[f], W[f * 64 + j], acc);
  out[(size_t)n * 64 + j] = f2bf(acc);
}

// ---------------- binned CSR build ----------------
__device__ __forceinline__ void edge_decode(int i,
    const int* __restrict__ sd_dst, const int* __restrict__ sd_src,
    const int* __restrict__ ve_var, const int* __restrict__ ve_emp,
    const int* __restrict__ vs_var, const int* __restrict__ vs_shift,
    int& b, int& lk, int& val) {
  if (i < ESD)            { int d = sd_dst[i]; b = d >> 6; lk = d & 63; val = sd_src[i]; }
  else if (i < ESD + EVE) { int j = i - ESD; int d = ve_var[j]; b = 469 + (d >> 11); lk = d & 2047; val = ve_emp[j]; }
  else                    { int j = i - ESD - EVE; int d = vs_var[j]; b = 714 + (d >> 11); lk = d & 2047; val = vs_shift[j]; }
}

__global__ __launch_bounds__(256) void bin_kernel(
    const int* __restrict__ sd_dst, const int* __restrict__ sd_src,
    const int* __restrict__ ve_var, const int* __restrict__ ve_emp,
    const int* __restrict__ vs_var, const int* __restrict__ vs_shift,
    uint2* __restrict__ staging, int* __restrict__ table) {
  __shared__ int hist[NBUCK];
  __shared__ int sums[256];
  int t = threadIdx.x, blk = blockIdx.x;
  int e0 = blk * CHUNK;
  int e1 = min(e0 + CHUNK, ET_ALL);
  int sbase = blk * SSTRIDE;
  for (int i = t; i < NBUCK; i += 256) hist[i] = 0;
  __syncthreads();
  for (int i = e0 + t; i < e1; i += 256) {
    int b, lk, val;
    edge_decode(i, sd_dst, sd_src, ve_var, ve_emp, vs_var, vs_shift, b, lk, val);
    atomicAdd(&hist[b], 1);
  }
  __syncthreads();
  int base = t * 4, v[4], s = 0;
  #pragma unroll
  for (int k = 0; k < 4; ++k) { int i = base + k; v[k] = (i < NBUCK) ? hist[i] : 0; s += v[k]; }
  sums[t] = s; __syncthreads();
  for (int o = 1; o < 256; o <<= 1) {
    int add = (t >= o) ? sums[t - o] : 0;
    __syncthreads(); sums[t] += add; __syncthreads();
  }
  int run = sums[t] - s;
  #pragma unroll
  for (int k = 0; k < 4; ++k) {
    int i = base + k;
    if (i < NBUCK) { hist[i] = run; table[i * NBLK0 + blk] = sbase + run; run += v[k]; }
  }
  if (t == 0) table[NBUCK * NBLK0 + blk] = sbase + (e1 - e0);
  __syncthreads();
  for (int i = e0 + t; i < e1; i += 256) {
    int b, lk, val;
    edge_decode(i, sd_dst, sd_src, ve_var, ve_emp, vs_var, vs_shift, b, lk, val);
    int pos = sbase + atomicAdd(&hist[b], 1);
    staging[pos] = make_uint2((unsigned)lk, (unsigned)val);
  }
}

__global__ __launch_bounds__(1024) void bstart_kernel(const int* __restrict__ table,
                                                      int* __restrict__ bstart) {
  __shared__ int histL[NBUCK];
  __shared__ int sd[1024];
  int t = threadIdx.x;
  for (int i = t; i < NBUCK; i += 1024) histL[i] = 0;
  __syncthreads();
  for (int idx = t; idx < NBUCK * NBLK0; idx += 1024) {
    int len = table[idx + NBLK0] - table[idx];
    if (len) atomicAdd(&histL[idx >> 8], len);
  }
  __syncthreads();
  int v = (t < NBUCK) ? histL[t] : 0;
  sd[t] = v; __syncthreads();
  for (int o = 1; o < 1024; o <<= 1) {
    int add = (t >= o) ? sd[t - o] : 0;
    __syncthreads(); sd[t] += add; __syncthreads();
  }
  if (t < NBUCK) bstart[t] = sd[t] - v;
  if (t == NBUCK - 1) bstart[NBUCK] = sd[t];
}

__global__ __launch_bounds__(256) void csr_build_kernel(
    const uint2* __restrict__ staging, const int* __restrict__ table,
    const int* __restrict__ bstart, int* __restrict__ row, int* __restrict__ elist) {
  __shared__ int segstart[NBLK0];
  __shared__ int cum[NBLK0];
  __shared__ int hist[2048];
  __shared__ int sums[256];
  int b = blockIdx.x, t = threadIdx.x;
  {
    int s0 = table[b * NBLK0 + t];
    int s1 = table[(b + 1) * NBLK0 + t];
    segstart[t] = s0;
    cum[t] = s1 - s0;
  }
  for (int i = t; i < 2048; i += 256) hist[i] = 0;
  __syncthreads();
  for (int o = 1; o < NBLK0; o <<= 1) {
    int add = (t >= o) ? cum[t - o] : 0;
    __syncthreads(); cum[t] += add; __syncthreads();
  }
  int total = cum[NBLK0 - 1];
  int keyBase, kcount;
  if (b < 469)      { keyBase = b * 64;                     kcount = min(64,   30000  - b * 64); }
  else if (b < 714) { int lb = b - 469; keyBase = 30000  + lb * 2048; kcount = min(2048, 500000 - lb * 2048); }
  else              { int lb = b - 714; keyBase = 530000 + lb * 2048; kcount = min(2048, 500000 - lb * 2048); }
  for (int idx = t; idx < total; idx += 256) {
    int lo = 0, hi = NBLK0 - 1;
    while (lo < hi) { int mid = (lo + hi) >> 1; if (cum[mid] > idx) hi = mid; else lo = mid + 1; }
    int off = idx - (lo ? cum[lo - 1] : 0);
    unsigned lk = staging[segstart[lo] + off].x;
    atomicAdd(&hist[lk], 1);
  }
  __syncthreads();
  int bs = bstart[b];
  int base = t * 8, v[8], s = 0;
  #pragma unroll
  for (int k = 0; k < 8; ++k) { int i = base + k; v[k] = (i < kcount) ? hist[i] : 0; s += v[k]; }
  sums[t] = s; __syncthreads();
  for (int o = 1; o < 256; o <<= 1) {
    int add = (t >= o) ? sums[t - o] : 0;
    __syncthreads(); sums[t] += add; __syncthreads();
  }
  int run = sums[t] - s;
  #pragma unroll
  for (int k = 0; k < 8; ++k) {
    int i = base + k;
    if (i < kcount) { hist[i] = run; row[keyBase + i] = bs + run; run += v[k]; }
  }
  if (b == NBUCK - 1 && t == 0) row[NT_CNT] = bstart[NBUCK];
  __syncthreads();
  for (int idx = t; idx < total; idx += 256) {
    int lo = 0, hi = NBLK0 - 1;
    while (lo < hi) { int mid = (lo + hi) >> 1; if (cum[mid] > idx) hi = mid; else lo = mid + 1; }
    int off = idx - (lo ? cum[lo - 1] : 0);
    uint2 p = staging[segstart[lo] + off];
    int pos = bs + atomicAdd(&hist[p.x], 1);
    elist[pos] = (int)p.y;
  }
}

// ---------------- Stage 1: GAT aggregate (bf16 gather of h_sh0, MFMA apply W) ---------
__global__ __launch_bounds__(512) void gat_aggr_kernel(
    const float* __restrict__ h_sh0, const unsigned short* __restrict__ h_sh0b,
    const float* __restrict__ a_s, const float* __restrict__ a_d,
    const int* __restrict__ row, const int* __restrict__ elist,
    const unsigned short* __restrict__ Wrb, const float* __restrict__ gat_b,
    float* __restrict__ h_sh1, int N) {
  __shared__ float aggT[256][65];   // [k = h*64+f][node-col]
  int tid = threadIdx.x, lane = tid & 63;
  int w = __builtin_amdgcn_readfirstlane((int)(tid >> 6));
  int blockStart = blockIdx.x * 64;

  // phase 1: per-node alpha-weighted h_sh0 accumulation (wave per node, lane = feature)
  for (int k = 0; k < 8; ++k) {
    int c = w * 8 + k;
    int n = blockStart + c;
    float4 ad4 = make_float4(0.f, 0.f, 0.f, 0.f);
    int b = 0, e = 0;
    if (n < N) { b = row[n]; e = row[n + 1]; ad4 = *(const float4*)(a_d + n * 4); }
    float g0 = 0, g1 = 0, g2 = 0, g3 = 0, z0 = 0, z1 = 0, z2 = 0, z3 = 0;
    for (int p = b; p < e; ++p) {
      int s = elist[p];
      const float4 as4 = *(const float4*)(a_s + s * 4);
      float e0 = as4.x + ad4.x, e1 = as4.y + ad4.y;
      float e2 = as4.z + ad4.z, e3 = as4.w + ad4.w;
      e0 = e0 > 0.f ? e0 : 0.2f * e0;  e1 = e1 > 0.f ? e1 : 0.2f * e1;
      e2 = e2 > 0.f ? e2 : 0.2f * e2;  e3 = e3 > 0.f ? e3 : 0.2f * e3;
      float x0 = __expf(e0), x1 = __expf(e1), x2 = __expf(e2), x3 = __expf(e3);
      float hv = bf2f(h_sh0b[(size_t)s * 64 + lane]);
      z0 += x0; z1 += x1; z2 += x2; z3 += x3;
      g0 = fmaf(x0, hv, g0); g1 = fmaf(x1, hv, g1);
      g2 = fmaf(x2, hv, g2); g3 = fmaf(x3, hv, g3);
    }
    aggT[lane][c]       = g0 / fmaxf(z0, 1e-16f);
    aggT[64 + lane][c]  = g1 / fmaxf(z1, 1e-16f);
    aggT[128 + lane][c] = g2 / fmaxf(z2, 1e-16f);
    aggT[192 + lane][c] = g3 / fmaxf(z3, 1e-16f);
  }
  __syncthreads();

  // phase 2: h_sh1 = relu(agg @ Wr + b) + h_sh0   via bf16 MFMA (0.25 folded in Wr)
  {
    int mtile = w >> 1;
    int row16 = lane & 15, blk = lane >> 4;
    int mrow = mtile * 16 + row16;
    #pragma unroll
    for (int t = 0; t < 2; ++t) {
      int ntile = (w & 1) * 2 + t;
      f32x4 acc = {0.f, 0.f, 0.f, 0.f};
      #pragma unroll
      for (int kb = 0; kb < 8; ++kb) {
        short8 a;
        #pragma unroll
        for (int i = 0; i < 8; ++i)
          a[i] = (short)f2bf(aggT[kb * 32 + blk * 8 + i][mrow]);
        short8 bfr = *(const short8*)(Wrb + (((ntile * 8 + kb) * 64 + lane) << 3));
        acc = __builtin_amdgcn_mfma_f32_16x16x32_bf16(a, bfr, acc, 0, 0, 0);
      }
      int j = ntile * 16 + row16;
      float gb = gat_b[j];
      #pragma unroll
      for (int r = 0; r < 4; ++r) {
        int node = blockStart + mtile * 16 + blk * 4 + r;
        if (node < N) {
          float o = fmaxf(acc[r] + gb, 0.0f) + h_sh0[(size_t)node * 64 + j];
          h_sh1[(size_t)node * 64 + j] = o;
        }
      }
    }
  }
}

// ---------------- Stage 2+3 fused: var-proj + inject x2 + MFMA fuse + L2 norm ----------
__global__ __launch_bounds__(512) void stage2_kernel(
    const float* __restrict__ x_var, const float* __restrict__ W_var,
    const float* __restrict__ b_var,
    const unsigned short* __restrict__ K2e, const unsigned short* __restrict__ Vpe,
    const int* __restrict__ ve_row, const int* __restrict__ ve_src,
    const unsigned short* __restrict__ K2s, const unsigned short* __restrict__ Vps,
    const int* __restrict__ vs_row, const int* __restrict__ vs_src,
    const unsigned short* __restrict__ fuseWb, const float* __restrict__ fuseb,
    float* __restrict__ out, int N) {
  __shared__ float fT[192][65];   // [feature][node-col]
  __shared__ float ssq2[64][2];
  int tid = threadIdx.x;
  int lane = tid & 63;
  int w = __builtin_amdgcn_readfirstlane((int)(tid >> 6));   // 0..7
  int g = lane >> 4, sl = lane & 15;
  int blockStart = blockIdx.x * 64;

  // ---- Phase A: var-proj (coalesced + shfl broadcast) + injections ----
  for (int k = 0; k < 2; ++k) {
    int c = w * 8 + k * 4 + g;
    int n = blockStart + c;
    bool act = (n < N);
    // subgroup-cooperative x row load: 1-2 coalesced scalars per lane
    float x0 = 0.f, x1 = 0.f;
    if (act) {
      x0 = x_var[(size_t)n * 19 + sl];
      if (sl < 3) x1 = x_var[(size_t)n * 19 + 16 + sl];
    }
    int sgbase = lane & 48;
    float4 a4 = *(const float4*)(b_var + sl * 4);
    #pragma unroll
    for (int f = 0; f < 19; ++f) {
      float xf = (f < 16) ? __shfl(x0, sgbase + f)
                          : __shfl(x1, sgbase + (f - 16));
      const float4 w4 = *(const float4*)(W_var + f * 64 + sl * 4);
      a4.x = fmaf(xf, w4.x, a4.x); a4.y = fmaf(xf, w4.y, a4.y);
      a4.z = fmaf(xf, w4.z, a4.z); a4.w = fmaf(xf, w4.w, a4.w);
    }
    float4 hv;
    hv.x = act ? fmaxf(a4.x, 0.f) : 0.f;
    hv.y = act ? fmaxf(a4.y, 0.f) : 0.f;
    hv.z = act ? fmaxf(a4.z, 0.f) : 0.f;
    hv.w = act ? fmaxf(a4.w, 0.f) : 0.f;
    fT[sl * 4 + 0][c] = hv.x; fT[sl * 4 + 1][c] = hv.y;
    fT[sl * 4 + 2][c] = hv.z; fT[sl * 4 + 3][c] = hv.w;

    #pragma unroll
    for (int which = 0; which < 2; ++which) {
      const int* rowp = which ? vs_row : ve_row;
      const int* srcp = which ? vs_src : ve_src;
      const unsigned short* K2 = which ? K2s : K2e;
      const unsigned short* Vp = which ? Vps : Vpe;
      int outBase = which ? 128 : 64;
      int b = 0, e = 0;
      if (act) { b = rowp[n]; e = rowp[n + 1]; }
      float4 acc = make_float4(0.f, 0.f, 0.f, 0.f);
      float z = 0.0f;
      for (int p = b; p < e; ++p) {
        int s = srcp[p];
        const ushort4 ku = *(const ushort4*)(K2 + (size_t)s * 64 + sl * 4);
        float part = hv.x * bf2f(ku.x) + hv.y * bf2f(ku.y)
                   + hv.z * bf2f(ku.z) + hv.w * bf2f(ku.w);
        part += __shfl_xor(part, 1); part += __shfl_xor(part, 2);
        part += __shfl_xor(part, 4); part += __shfl_xor(part, 8);
        float ex = __expf(part);
        z += ex;
        const ushort4 vu = *(const ushort4*)(Vp + (size_t)s * 64 + sl * 4);
        acc.x = fmaf(ex, bf2f(vu.x), acc.x); acc.y = fmaf(ex, bf2f(vu.y), acc.y);
        acc.z = fmaf(ex, bf2f(vu.z), acc.z); acc.w = fmaf(ex, bf2f(vu.w), acc.w);
      }
      float inv = (e > b) ? 1.0f / fmaxf(z, 1e-9f) : 0.0f;
      fT[outBase + sl * 4 + 0][c] = acc.x * inv;
      fT[outBase + sl * 4 + 1][c] = acc.y * inv;
      fT[outBase + sl * 4 + 2][c] = acc.z * inv;
      fT[outBase + sl * 4 + 3][c] = acc.w * inv;
    }
  }
  __syncthreads();

  // ---- Phase B: fuse matmul via bf16 MFMA 16x16x32 ----
  {
    int mtile = w >> 1;
    int row16 = lane & 15, blk = lane >> 4;
    int mrow = mtile * 16 + row16;
    float nodeSS[4] = {0.f, 0.f, 0.f, 0.f};
    #pragma unroll
    for (int t = 0; t < 2; ++t) {
      int ntile = (w & 1) * 2 + t;
      f32x4 acc = {0.f, 0.f, 0.f, 0.f};
      #pragma unroll
      for (int kb = 0; kb < 6; ++kb) {
        short8 a;
        #pragma unroll
        for (int i = 0; i < 8; ++i)
          a[i] = (short)f2bf(fT[kb * 32 + blk * 8 + i][mrow]);
        short8 bfr = *(const short8*)(fuseWb + (((ntile * 6 + kb) * 64 + lane) << 3));
        acc = __builtin_amdgcn_mfma_f32_16x16x32_bf16(a, bfr, acc, 0, 0, 0);
      }
      float fb = fuseb[ntile * 16 + row16];
      #pragma unroll
      for (int r = 0; r < 4; ++r) {
        float v = fmaxf(acc[r] + fb, 0.0f);
        float vv = v * v;
        vv += __shfl_xor(vv, 1); vv += __shfl_xor(vv, 2);
        vv += __shfl_xor(vv, 4); vv += __shfl_xor(vv, 8);
        nodeSS[r] += vv;
      }
    }
    if (row16 == 0) {
      #pragma unroll
      for (int r = 0; r < 4; ++r)
        ssq2[mtile * 16 + blk * 4 + r][w & 1] = nodeSS[r];
    }
  }
  __syncthreads();
  if (tid < 64) {
    int n = blockStart + tid;
    if (n < N) out[n] = sqrtf(ssq2[tid][0] + ssq2[tid][1]);
  }
}

// ---------------- host ----------------
extern "C" void kernel_launch(void* const* d_in, const int* in_sizes, int n_in,
                              void* d_out, int out_size, void* d_ws, size_t ws_size,
                              hipStream_t stream) {
  const float* x_emp   = (const float*)d_in[0];
  const float* x_shift = (const float*)d_in[1];
  const float* x_var   = (const float*)d_in[2];
  const float* W_emp   = (const float*)d_in[4];
  const float* b_emp   = (const float*)d_in[5];
  const float* W_shift = (const float*)d_in[6];
  const float* b_shift = (const float*)d_in[7];
  const float* W_var   = (const float*)d_in[8];
  const float* b_var   = (const float*)d_in[9];
  const float* gat_W   = (const float*)d_in[12];
  const float* att_s   = (const float*)d_in[13];
  const float* att_d   = (const float*)d_in[14];
  const float* gat_b   = (const float*)d_in[15];
  const float* injW_e  = (const float*)d_in[16];
  const float* injb_e  = (const float*)d_in[17];
  const float* injW_s  = (const float*)d_in[18];
  const float* injb_s  = (const float*)d_in[19];
  const float* qW_e    = (const float*)d_in[20];
  const float* kW_e    = (const float*)d_in[21];
  const float* qW_s    = (const float*)d_in[22];
  const float* kW_s    = (const float*)d_in[23];
  const float* fuseW   = (const float*)d_in[24];
  const float* fuseb   = (const float*)d_in[25];
  const int* sd_src  = (const int*)d_in[26];
  const int* sd_dst  = (const int*)d_in[27];
  const int* ve_var  = (const int*)d_in[28];
  const int* ve_emp  = (const int*)d_in[29];
  const int* vs_var  = (const int*)d_in[30];
  const int* vs_shift= (const int*)d_in[31];
  float* out = (float*)d_out;

  char* base = (char*)d_ws;
  size_t off = 0;
  auto A = [&](size_t nbytes) -> void* {
    void* r = base + off;
    off = (off + nbytes + 255) & ~(size_t)255;
    return r;
  };
  float* h_emp = (float*)A((size_t)NEMP * 64 * 4);
  float* h_sh0 = (float*)A((size_t)NSHIFT * 64 * 4);
  unsigned short* h_sh0b = (unsigned short*)A((size_t)NSHIFT * 64 * 2);
  float* h_sh1 = (float*)A((size_t)NSHIFT * 64 * 4);
  float* a_s   = (float*)A((size_t)NSHIFT * 4 * 4);
  float* a_d   = (float*)A((size_t)NSHIFT * 4 * 4);
  unsigned short* Vpe = (unsigned short*)A((size_t)NEMP * 64 * 2);
  unsigned short* K2e = (unsigned short*)A((size_t)NEMP * 64 * 2);
  unsigned short* Vps = (unsigned short*)A((size_t)NSHIFT * 64 * 2);
  unsigned short* K2s = (unsigned short*)A((size_t)NSHIFT * 64 * 2);
  float* W2e   = (float*)A((size_t)64 * 64 * 4);
  float* W2s   = (float*)A((size_t)64 * 64 * 4);
  float* w_as  = (float*)A((size_t)64 * 4 * 4);
  float* w_ad  = (float*)A((size_t)64 * 4 * 4);
  unsigned short* fuseWb = (unsigned short*)A((size_t)192 * 64 * 2);
  unsigned short* Wrb    = (unsigned short*)A((size_t)256 * 64 * 2);
  int* row_all = (int*)A((size_t)(NT_CNT + 1) * 4);
  int* el_all  = (int*)A((size_t)ET_ALL * 4);
  uint2* staging = (uint2*)A((size_t)NBLK0 * SSTRIDE * 8);
  int* table   = (int*)A((size_t)(NBUCK + 1) * NBLK0 * 4);
  int* bstart  = (int*)A((size_t)(NBUCK + 1) * 4);

  // prep (weight folds) first: proj_all depends on w_as/w_ad
  small_prep_kernel<<<5, 256, 0, stream>>>(qW_e, kW_e, qW_s, kW_s, fuseW, gat_W,
                                           att_s, att_d, W2e, W2s, fuseWb,
                                           w_as, w_ad, Wrb);

  // binned CSR over {sd, ve, vs}
  bin_kernel<<<NBLK0, 256, 0, stream>>>(sd_dst, sd_src, ve_var, ve_emp,
                                        vs_var, vs_shift, staging, table);
  bstart_kernel<<<1, 1024, 0, stream>>>(table, bstart);
  csr_build_kernel<<<NBUCK, 256, 0, stream>>>(staging, table, bstart, row_all, el_all);

  // Stage 0: emp + shift projections (+ fused a_s/a_d + bf16 copy)
  proj_all_kernel<<<750 + 7500, 256, 0, stream>>>(
      x_emp, W_emp, b_emp, h_emp,
      x_shift, W_shift, b_shift, h_sh0, h_sh0b,
      w_as, w_ad, a_s, a_d);

  // Stage 1: GAT (bf16 gather + MFMA weight apply)
  gat_aggr_kernel<<<(NSHIFT + 63) / 64, 512, 0, stream>>>(
      h_sh0, h_sh0b, a_s, a_d, row_all, el_all, Wrb, gat_b, h_sh1, NSHIFT);

  // Stage 2 prep (bf16 outputs)
  linear_all_kernel<<<16500, 256, 0, stream>>>(h_emp, h_sh1,
      injW_e, injb_e, W2e, injW_s, injb_s, W2s, Vpe, K2e, Vps, K2s);

  // Stage 2+3 fused
  stage2_kernel<<<(NVAR + 63) / 64, 512, 0, stream>>>(x_var, W_var, b_var,
      K2e, Vpe, row_all + NSHIFT, el_all,
      K2s, Vps, row_all + NSHIFT + NVAR, el_all,
      fuseWb, fuseb, out, NVAR);
}